// Round 20
// baseline (242.910 us; speedup 1.0000x reference)
//
#include <hip/hip_runtime.h>
#include <hip/hip_bf16.h>
#include <math.h>

#define DIM 256
#define KCODES 8192
#define BN_TOTAL 32768

// d_out flat f32 layout (reference return order)
#define OUT_IND 8388608
#define OUT_LOSS 8421376
#define OUT_CS 8421377
#define OUT_ES 8429569
#define OUT_TOTAL 10526721

// scratch-in-output offsets (f32 units)
#define XI8_OFF 0            // x i8 [32768][256] = 8 MB, dead after mfma
#define CI8_OFF 4194304      // cb i8 [8192][256] (swizzled) = 2 MB, dead after mfma
#define PART_OFF OUT_ES      // partials int2[32768][32] = 8 MB (exact fit), dead after pick

typedef unsigned short u16;
typedef unsigned char u8;
typedef unsigned int u32;
typedef __attribute__((ext_vector_type(4))) int i32x4;
typedef __attribute__((address_space(1))) const void gvoid_t;
typedef __attribute__((address_space(3))) void lvoid_t;

#define QSCALE (127.0f / 6.0f)
#define INV_2S2 (16129.0f / 72.0f)   // 1/(2*s^2), s = 6/127

// ---- prep: x -> i8 (linear); cb -> i8 (chunk-swizzled) + exact c2 + c2i ----
__global__ __launch_bounds__(256) void vq_prep(const float* __restrict__ x,
                                               const float* __restrict__ cb,
                                               u8* __restrict__ Xi8,
                                               u8* __restrict__ Ci8,
                                               float* __restrict__ c2,
                                               int* __restrict__ c2i) {
  int b = blockIdx.x;
  bool isx = (b < 2048);
  int g = (isx ? b : (b - 2048)) * 256 + threadIdx.x;
  int row = g >> 4;            // x row or code
  int chunk = g & 15;          // 16-element (16B) chunk
  const float* src = (isx ? x : cb) + (size_t)row * DIM + chunk * 16;
  float vv[16];
#pragma unroll
  for (int q = 0; q < 4; ++q) {
    float4 v = *(const float4*)(src + q * 4);
    vv[q * 4 + 0] = v.x; vv[q * 4 + 1] = v.y;
    vv[q * 4 + 2] = v.z; vv[q * 4 + 3] = v.w;
  }
  u32 w[4];
  float s = 0.0f;
#pragma unroll
  for (int q = 0; q < 4; ++q) {
    u32 acc = 0;
#pragma unroll
    for (int e = 0; e < 4; ++e) {
      float v = vv[q * 4 + e];
      s += v * v;
      float vs = fminf(fmaxf(v * QSCALE, -127.0f), 127.0f);
      int iv = (int)rintf(vs);
      acc |= ((u32)(u8)(char)iv) << (8 * e);
    }
    w[q] = acc;
  }
  uint4 pk = {w[0], w[1], w[2], w[3]};
  if (isx) {
    *(uint4*)(Xi8 + (size_t)row * DIM + chunk * 16) = pk;
  } else {
    // swizzle: 16B chunk j of each 64B k-group stored at j ^ ((code>>1)&3)
    int kbg = chunk >> 2;
    int j = chunk & 3;
    int js = j ^ ((row >> 1) & 3);
    *(uint4*)(Ci8 + (size_t)row * DIM + kbg * 64 + js * 16) = pk;
#pragma unroll
    for (int m = 1; m <= 8; m <<= 1) s += __shfl_xor(s, m, 64);  // 16-lane grp
    if (chunk == 0) {
      c2[row] = s;
      c2i[row] = (int)rintf((s - 256.0f) * INV_2S2);
    }
  }
}

// ------------- main: barrier-free wave-async i8 MFMA + int-key top-2 -------
// r19's proven wave-private-ring protocol, NSPLIT=8 for 4 waves/SIMD TLP:
// each wave = 64 rows x one 1024-code split, private 2x4KB ring staged via
// global_load_lds, synced ONLY by counted s_waitcnt vmcnt(4). Preloads
// drained by vmcnt(0) before ring counting; ZERO non-stage VMEM in loop
// (c2i in LDS behind the single block barrier). Same-wave produce/consume
// -> deterministic by construction.
__global__ __launch_bounds__(256, 4)
void vq_mfma(const u8* __restrict__ XB, const u8* __restrict__ CBb,
             const int* __restrict__ c2i, int2* __restrict__ partials) {
  __shared__ __align__(16) u8 ring[4][2][4096];   // wave-private rings, 32 KB
  __shared__ __align__(16) int c2s[1024];         // split's c2i, 4 KB
  const int t = threadIdx.x;
  const int wid = t >> 6;
  const int lane = t & 63;
  const int lhi = lane >> 4, llo = lane & 15;
  const int sl = lhi ^ ((llo >> 1) & 3);
  const int rg = blockIdx.x & 127;   // 128 row-groups of 256 rows
  const int s = blockIdx.x >> 7;     // split 0..7
  const int wrow0 = rg * 256 + wid * 64;
  const int codeS0 = s * 1024;

  // preload x fragments: b[n][kb] = 16 i8 at row (wrow0+n*16+llo), K=kb*64+lhi*16
  i32x4 b[4][4];
#pragma unroll
  for (int n = 0; n < 4; ++n) {
    const u8* bp = XB + (size_t)(wrow0 + n * 16 + llo) * DIM + lhi * 16;
#pragma unroll
    for (int kb = 0; kb < 4; ++kb) b[n][kb] = *(const i32x4*)(bp + kb * 64);
  }
  // c2i -> LDS (each wave stages its 256-int quarter of the split)
  {
    const int* cp = c2i + codeS0 + wid * 256 + lane * 4;
    char* cd = (char*)c2s + wid * 1024;
    __builtin_amdgcn_global_load_lds((gvoid_t*)cp, (lvoid_t*)cd, 16, 0, 0);
  }
  asm volatile("s_waitcnt vmcnt(0)" ::: "memory");  // drain ALL preloads
  __builtin_amdgcn_sched_barrier(0);
  __syncthreads();  // publish c2s -- the ONLY block barrier in this kernel

  // wave-private stage pointers: linear copy of the stored (swizzled) rows;
  // swizzle is resolved at the LDS READ (sl), as verified r15-r19.
  const u8* sp0 = CBb + (size_t)(codeS0 + (lane >> 2)) * DIM + (lane & 3) * 16;
  const u8* sp1 = sp0 + (size_t)16 * DIM;
  const u8* sp2 = sp0 + (size_t)32 * DIM;
  const u8* sp3 = sp0 + (size_t)48 * DIM;
  char* rb = (char*)&ring[wid][0][0];
  const int aoff = llo * 64 + sl * 16;

  int v1[4], v2[4];
#pragma unroll
  for (int n = 0; n < 4; ++n) { v1[n] = 0x7FFFFFFF; v2[n] = 0x7FFFFFFF; }

// stage one 4KB chunk (64 codes x 64B k-group) into ring buf BUF
#define STG(BUF, IMM)                                                          \
  __builtin_amdgcn_global_load_lds((gvoid_t*)(sp0 + (IMM)),                    \
      (lvoid_t*)(rb + (BUF) * 4096 + 0), 16, 0, 0);                            \
  __builtin_amdgcn_global_load_lds((gvoid_t*)(sp1 + (IMM)),                    \
      (lvoid_t*)(rb + (BUF) * 4096 + 1024), 16, 0, 0);                         \
  __builtin_amdgcn_global_load_lds((gvoid_t*)(sp2 + (IMM)),                    \
      (lvoid_t*)(rb + (BUF) * 4096 + 2048), 16, 0, 0);                         \
  __builtin_amdgcn_global_load_lds((gvoid_t*)(sp3 + (IMM)),                    \
      (lvoid_t*)(rb + (BUF) * 4096 + 3072), 16, 0, 0);

// one k-step: wait own ring (vmcnt(4): <=8 outstanding, FIFO retires the
// needed stage), read 4 a-frags, 16 MFMA. KB compile-time.
#define VQMM(KB)                                                               \
  {                                                                            \
    __builtin_amdgcn_sched_barrier(0);                                         \
    asm volatile("s_waitcnt vmcnt(4)" ::: "memory");                           \
    __builtin_amdgcn_sched_barrier(0);                                         \
    const char* asrc = rb + ((KB) & 1) * 4096;                                 \
    i32x4 a0 = *(const i32x4*)(asrc + 0 + aoff);                               \
    i32x4 a1 = *(const i32x4*)(asrc + 1024 + aoff);                            \
    i32x4 a2 = *(const i32x4*)(asrc + 2048 + aoff);                            \
    i32x4 a3 = *(const i32x4*)(asrc + 3072 + aoff);                            \
    _Pragma("unroll")                                                          \
    for (int n = 0; n < 4; ++n) {                                              \
      acc[0][n] = __builtin_amdgcn_mfma_i32_16x16x64_i8(a0, b[n][KB], acc[0][n], 0, 0, 0); \
      acc[1][n] = __builtin_amdgcn_mfma_i32_16x16x64_i8(a1, b[n][KB], acc[1][n], 0, 0, 0); \
      acc[2][n] = __builtin_amdgcn_mfma_i32_16x16x64_i8(a2, b[n][KB], acc[2][n], 0, 0, 0); \
      acc[3][n] = __builtin_amdgcn_mfma_i32_16x16x64_i8(a3, b[n][KB], acc[3][n], 0, 0, 0); \
    }                                                                          \
  }

  STG(0, 0);   // prologue: chunk (ct=0, kb=0) -> buf 0

#pragma unroll 1
  for (int ct = 0; ct < 16; ++ct) {
    i32x4 acc[4][4];
#pragma unroll
    for (int m = 0; m < 4; ++m)
#pragma unroll
      for (int n = 0; n < 4; ++n) acc[m][n] = (i32x4){0, 0, 0, 0};

    STG(1, 64);   VQMM(0)
    STG(0, 128);  VQMM(1)
    STG(1, 192);  VQMM(2)
    sp0 += 16384; sp1 += 16384; sp2 += 16384; sp3 += 16384;  // -> ct+1 base
    STG(0, 0);    VQMM(3)   // stages (ct+1, kb=0); at ct=15: dead in-bounds read

    // epilogue: key = ((c2i - dot) << 13) + code; running top-2 per lane-slice
    const int ctb = ct * 256;
#pragma unroll
    for (int m = 0; m < 4; ++m) {
      int4 cv = *(const int4*)((const char*)c2s + ctb + m * 64 + lhi * 16);
      int cbase = codeS0 + ct * 64 + m * 16 + lhi * 4;
      int cvv[4] = {cv.x, cv.y, cv.z, cv.w};
#pragma unroll
      for (int n = 0; n < 4; ++n) {
#pragma unroll
        for (int r = 0; r < 4; ++r) {
          int diff = cvv[r] - acc[m][n][r];
          int key = (int)(((u32)diff << 13) + (u32)(cbase + r));
          int ov1 = v1[n];
          v1[n] = min(key, ov1);
          v2[n] = min(v2[n], max(key, ov1));
        }
      }
    }
  }
#undef STG
#undef VQMM
  asm volatile("s_waitcnt vmcnt(0)" ::: "memory");  // drain before exit

  // write top-2 per (row, slice); slot = s*4 + lhi; unique writer per slot.
#pragma unroll
  for (int n = 0; n < 4; ++n) {
    int row = wrow0 + n * 16 + llo;
    int slot = s * 4 + lhi;
    partials[(size_t)row * 32 + slot] = make_int2(v1[n], v2[n]);
  }
}

// ---- pick: 64 cands (32 slices x2) -> top-4 -> exact f32 rescore ----
__global__ __launch_bounds__(256)
void vq_pick(const float* __restrict__ x, const float* __restrict__ cb,
             const float* __restrict__ c2g, const int2* __restrict__ partials,
             int* __restrict__ ind, float* __restrict__ out_ind,
             float* __restrict__ out_q, int* __restrict__ cnt,
             float* __restrict__ loss_part) {
  __shared__ float lsm[4];
  int wid = threadIdx.x >> 6, lane = threadIdx.x & 63;
  int row = blockIdx.x * 4 + wid;
  int cv = 0x7FFFFFFF, cv2 = 0x7FFFFFFF;
  if (lane < 32) {
    int2 p = partials[(size_t)row * 32 + lane];
    cv = p.x; cv2 = p.y;
  }
  int cand[4];
#pragma unroll
  for (int rsel = 0; rsel < 4; ++rsel) {
    int bv = cv;
#pragma unroll
    for (int mask = 1; mask < 32; mask <<= 1)
      bv = min(bv, __shfl_xor(bv, mask, 64));
    bv = __shfl(bv, 0, 64);
    cand[rsel] = bv & 8191;
    if (cv == bv) { cv = cv2; cv2 = 0x7FFFFFFF; }
  }
  const float4 xv = *(const float4*)(x + (size_t)row * DIM + lane * 4);
  float4 q0 = *(const float4*)(cb + (size_t)cand[0] * DIM + lane * 4);
  float4 q1 = *(const float4*)(cb + (size_t)cand[1] * DIM + lane * 4);
  float4 q2 = *(const float4*)(cb + (size_t)cand[2] * DIM + lane * 4);
  float4 q3 = *(const float4*)(cb + (size_t)cand[3] * DIM + lane * 4);
  float d0 = xv.x * q0.x + xv.y * q0.y + xv.z * q0.z + xv.w * q0.w;
  float d1 = xv.x * q1.x + xv.y * q1.y + xv.z * q1.z + xv.w * q1.w;
  float d2 = xv.x * q2.x + xv.y * q2.y + xv.z * q2.z + xv.w * q2.w;
  float d3 = xv.x * q3.x + xv.y * q3.y + xv.z * q3.z + xv.w * q3.w;
  float x2 = xv.x * xv.x + xv.y * xv.y + xv.z * xv.z + xv.w * xv.w;
#pragma unroll
  for (int mask = 1; mask < 64; mask <<= 1) {
    d0 += __shfl_xor(d0, mask, 64);
    d1 += __shfl_xor(d1, mask, 64);
    d2 += __shfl_xor(d2, mask, 64);
    d3 += __shfl_xor(d3, mask, 64);
    x2 += __shfl_xor(x2, mask, 64);
  }
  float e0 = fmaf(-2.0f, d0, c2g[cand[0]]);
  float e1 = fmaf(-2.0f, d1, c2g[cand[1]]);
  float e2 = fmaf(-2.0f, d2, c2g[cand[2]]);
  float e3 = fmaf(-2.0f, d3, c2g[cand[3]]);
  float best = e0; int bk = cand[0];
  if (e1 < best || (e1 == best && cand[1] < bk)) { best = e1; bk = cand[1]; }
  if (e2 < best || (e2 == best && cand[2] < bk)) { best = e2; bk = cand[2]; }
  if (e3 < best || (e3 == best && cand[3] < bk)) { best = e3; bk = cand[3]; }
  float4 q = (bk == cand[1]) ? q1 : (bk == cand[2]) ? q2 : (bk == cand[3]) ? q3 : q0;
  *(float4*)(out_q + (size_t)row * DIM + lane * 4) = q;
  if (lane == 0) {
    ind[row] = bk;
    out_ind[row] = (float)bk;
    atomicAdd(cnt + bk, 1);
    lsm[wid] = x2 + best;   // == ||q - x||^2 (exact identity)
  }
  __syncthreads();
  if (threadIdx.x == 0)
    loss_part[blockIdx.x] = lsm[0] + lsm[1] + lsm[2] + lsm[3];
}

// ---- scan: exclusive scan cnt -> offs/woffs; out_cs; reduce loss ----
__global__ __launch_bounds__(1024)
void vq_scan(const int* __restrict__ cnt, int* __restrict__ offs,
             int* __restrict__ woffs, float* __restrict__ out_cs,
             const float* __restrict__ loss_part, float* __restrict__ out_loss) {
  __shared__ int ssum[1024];
  __shared__ float sls[1024];
  int tid = threadIdx.x;
  int c[8], loc[8];
  int s = 0;
#pragma unroll
  for (int j = 0; j < 8; ++j) {
    c[j] = cnt[tid * 8 + j];
    loc[j] = s;
    s += c[j];
  }
  ssum[tid] = s;
  float ls = 0.0f;
#pragma unroll
  for (int j = 0; j < 8; ++j) ls += loss_part[tid * 8 + j];
  sls[tid] = ls;
  __syncthreads();
  for (int off = 1; off < 1024; off <<= 1) {
    int v = (tid >= off) ? ssum[tid - off] : 0;
    __syncthreads();
    ssum[tid] += v;
    __syncthreads();
  }
  int base = (tid > 0) ? ssum[tid - 1] : 0;
#pragma unroll
  for (int j = 0; j < 8; ++j) {
    int o = base + loc[j];
    offs[tid * 8 + j] = o;
    woffs[tid * 8 + j] = o;
    out_cs[tid * 8 + j] = (float)c[j];
  }
  for (int off = 512; off >= 1; off >>= 1) {
    if (tid < off) sls[tid] += sls[tid + off];
    __syncthreads();
  }
  if (tid == 0) *out_loss = sls[0] * (1.0f / 8388608.0f);
}

// ---- scatter: build rowlist grouped by code ----
__global__ __launch_bounds__(256)
void vq_scatter(const int* __restrict__ ind, int* __restrict__ woffs,
                int* __restrict__ rowlist) {
  int row = blockIdx.x * 256 + threadIdx.x;
  int k = ind[row];
  int pos = atomicAdd(woffs + k, 1);
  rowlist[pos] = row;
}

// ---- esum: ONE BLOCK (4 waves) PER CODE; unroll-4 ILP; LDS cross-wave ----
__global__ __launch_bounds__(256)
void vq_esum(const float* __restrict__ x, const int* __restrict__ offs,
             const int* __restrict__ cnt, const int* __restrict__ rowlist,
             float* __restrict__ out_es) {
  __shared__ float4 sred[3][64];
  int k = blockIdx.x;
  int wid = threadIdx.x >> 6, lane = threadIdx.x & 63;
  int start = offs[k], n = cnt[k];
  const int* rl = rowlist + start;
  int jb = (n * wid) >> 2, je = (n * (wid + 1)) >> 2;
  float4 acc = {0.f, 0.f, 0.f, 0.f};
  int j = jb;
  for (; j + 4 <= je; j += 4) {
    int r0 = rl[j], r1 = rl[j + 1], r2 = rl[j + 2], r3 = rl[j + 3];
    float4 v0 = *(const float4*)(x + (size_t)r0 * DIM + lane * 4);
    float4 v1 = *(const float4*)(x + (size_t)r1 * DIM + lane * 4);
    float4 v2 = *(const float4*)(x + (size_t)r2 * DIM + lane * 4);
    float4 v3 = *(const float4*)(x + (size_t)r3 * DIM + lane * 4);
    acc.x += v0.x + v1.x + v2.x + v3.x;
    acc.y += v0.y + v1.y + v2.y + v3.y;
    acc.z += v0.z + v1.z + v2.z + v3.z;
    acc.w += v0.w + v1.w + v2.w + v3.w;
  }
  for (; j < je; ++j) {
    int r = rl[j];
    float4 v = *(const float4*)(x + (size_t)r * DIM + lane * 4);
    acc.x += v.x; acc.y += v.y; acc.z += v.z; acc.w += v.w;
  }
  if (wid > 0) sred[wid - 1][lane] = acc;
  __syncthreads();
  if (wid == 0) {
    float4 a1 = sred[0][lane], a2 = sred[1][lane], a3 = sred[2][lane];
    acc.x += a1.x + a2.x + a3.x;
    acc.y += a1.y + a2.y + a3.y;
    acc.z += a1.z + a2.z + a3.z;
    acc.w += a1.w + a2.w + a3.w;
    *(float4*)(out_es + (size_t)k * DIM + lane * 4) = acc;
  }
}

extern "C" void kernel_launch(void* const* d_in, const int* in_sizes, int n_in,
                              void* d_out, int out_size, void* d_ws,
                              size_t ws_size, hipStream_t stream) {
  const float* x = (const float*)d_in[0];
  const float* cb = (const float*)d_in[1];
  float* out = (float*)d_out;
  float* out_q = out;
  float* out_ind = out + OUT_IND;
  float* out_loss = out + OUT_LOSS;
  float* out_cs = out + OUT_CS;
  float* out_es = out + OUT_ES;

  // Scratch-in-output (r16-19-proven layout; partials = exact out_es fit):
  u8* Xi8 = (u8*)(out + XI8_OFF);
  u8* Ci8 = (u8*)(out + CI8_OFF);
  int2* partials = (int2*)(out + PART_OFF);

  // ws layout (448 KB; >= 2.21 MB proven available in round 1)
  char* w = (char*)d_ws;
  int* cnt = (int*)w;                              // 32 KB [memset 0]
  int* offs = (int*)(w + (32 << 10));              // 32 KB
  int* woffs = (int*)(w + (64 << 10));             // 32 KB
  float* loss_part = (float*)(w + (96 << 10));     // 32 KB
  int* ind = (int*)(w + (128 << 10));              // 128 KB
  int* rowlist = (int*)(w + (256 << 10));          // 128 KB
  float* c2 = (float*)(w + (384 << 10));           // 32 KB
  int* c2i = (int*)(w + (416 << 10));              // 32 KB

  hipMemsetAsync(cnt, 0, KCODES * sizeof(int), stream);
  vq_prep<<<2560, 256, 0, stream>>>(x, cb, Xi8, Ci8, c2, c2i);
  vq_mfma<<<1024, 256, 0, stream>>>(Xi8, Ci8, c2i, partials);
  vq_pick<<<BN_TOTAL / 4, 256, 0, stream>>>(x, cb, c2, partials, ind, out_ind,
                                            out_q, cnt, loss_part);
  vq_scan<<<1, 1024, 0, stream>>>(cnt, offs, woffs, out_cs, loss_part, out_loss);
  vq_scatter<<<BN_TOTAL / 256, 256, 0, stream>>>(ind, woffs, rowlist);
  vq_esum<<<KCODES, 256, 0, stream>>>(x, offs, cnt, rowlist, out_es);
}

// Round 21
// 194.239 us; speedup vs baseline: 1.2506x; 1.2506x over previous
//
#include <hip/hip_runtime.h>
#include <hip/hip_bf16.h>
#include <math.h>

#define DIM 256
#define KCODES 8192
#define BN_TOTAL 32768

// d_out flat f32 layout (reference return order)
#define OUT_IND 8388608
#define OUT_LOSS 8421376
#define OUT_CS 8421377
#define OUT_ES 8429569
#define OUT_TOTAL 10526721

// scratch-in-output offsets (f32 units)
#define XI8_OFF 0            // x i8 [32768][256] = 8 MB, dead after mfma
#define CI8_OFF 4194304      // cb i8 [8192][256] (swizzled) = 2 MB, dead after mfma
#define PART_OFF OUT_ES      // partials int2[32768][16] = 4 MB, dead after pick

typedef unsigned short u16;
typedef unsigned char u8;
typedef unsigned int u32;
typedef __attribute__((ext_vector_type(4))) int i32x4;
typedef __attribute__((ext_vector_type(4))) short s16x4;
typedef __attribute__((address_space(1))) const void gvoid_t;
typedef __attribute__((address_space(3))) void lvoid_t;

#define QSCALE (127.0f / 6.0f)
#define INV_2S2 (16129.0f / 72.0f)   // 1/(2*s^2), s = 6/127

// ---- prep: x -> i8; cb -> i8 (chunk-swizzled) + exact c2 + i16 c2 scale ----
__global__ __launch_bounds__(256) void vq_prep(const float* __restrict__ x,
                                               const float* __restrict__ cb,
                                               u8* __restrict__ Xi8,
                                               u8* __restrict__ Ci8,
                                               float* __restrict__ c2,
                                               short* __restrict__ c2i16) {
  int b = blockIdx.x;
  bool isx = (b < 2048);
  int g = (isx ? b : (b - 2048)) * 256 + threadIdx.x;
  int row = g >> 4;            // x row or code
  int chunk = g & 15;          // 16-element (16B) chunk
  const float* src = (isx ? x : cb) + (size_t)row * DIM + chunk * 16;
  float vv[16];
#pragma unroll
  for (int q = 0; q < 4; ++q) {
    float4 v = *(const float4*)(src + q * 4);
    vv[q * 4 + 0] = v.x; vv[q * 4 + 1] = v.y;
    vv[q * 4 + 2] = v.z; vv[q * 4 + 3] = v.w;
  }
  u32 w[4];
  float s = 0.0f;
#pragma unroll
  for (int q = 0; q < 4; ++q) {
    u32 acc = 0;
#pragma unroll
    for (int e = 0; e < 4; ++e) {
      float v = vv[q * 4 + e];
      s += v * v;
      float vs = fminf(fmaxf(v * QSCALE, -127.0f), 127.0f);
      int iv = (int)rintf(vs);
      acc |= ((u32)(u8)(char)iv) << (8 * e);
    }
    w[q] = acc;
  }
  uint4 pk = {w[0], w[1], w[2], w[3]};
  if (isx) {
    *(uint4*)(Xi8 + (size_t)row * DIM + chunk * 16) = pk;
  } else {
    // swizzle: 16B chunk j of each 64B k-group stored at j ^ ((code>>1)&3)
    int kbg = chunk >> 2;
    int j = chunk & 3;
    int js = j ^ ((row >> 1) & 3);
    *(uint4*)(Ci8 + (size_t)row * DIM + kbg * 64 + js * 16) = pk;
#pragma unroll
    for (int m = 1; m <= 8; m <<= 1) s += __shfl_xor(s, m, 64);  // 16-lane grp
    if (chunk == 0) {
      c2[row] = s;
      float ci = rintf((s - 256.0f) * INV_2S2);
      ci = fminf(fmaxf(ci, -32000.0f), 32000.0f);
      c2i16[row] = (short)(int)ci;
    }
  }
}

// ------------- main: barrier-free wave-async i8 MFMA + int-key top-2 -------
// r19's proven wave-private-ring protocol x r18's small tile for 4 waves/SIMD:
// each wave = 32 rows x one 2048-code split (b[2][4]=32 VGPR + acc[4][2]=32
// AGPR ~ 95 unified <= 128 cap of (256,4) -- no spill, unlike r20's 64-row
// tile). Private 2x4KB LDS ring staged via global_load_lds, synced ONLY by
// counted s_waitcnt vmcnt(4). Preloads drained by vmcnt(0) before ring
// counting; ZERO non-stage VMEM in the loop (i16 c2 in LDS behind the single
// block barrier). Same-wave produce/consume -> deterministic by construction.
__global__ __launch_bounds__(256, 4)
void vq_mfma(const u8* __restrict__ XB, const u8* __restrict__ CBb,
             const short* __restrict__ c2i16, int2* __restrict__ partials) {
  __shared__ __align__(16) u8 ring[4][2][4096];   // wave-private rings, 32 KB
  __shared__ __align__(16) short c2s[2048];       // split's i16 c2, 4 KB
  const int t = threadIdx.x;
  const int wid = t >> 6;
  const int lane = t & 63;
  const int lhi = lane >> 4, llo = lane & 15;
  const int sl = lhi ^ ((llo >> 1) & 3);
  const int rg = blockIdx.x & 255;   // 256 row-groups of 128 rows
  const int s = blockIdx.x >> 8;     // split 0..3
  const int wrow0 = rg * 128 + wid * 32;
  const int codeS0 = s * 2048;

  // preload x fragments: b[n][kb] = 16 i8 at row (wrow0+n*16+llo), K=kb*64+lhi*16
  i32x4 b[2][4];
#pragma unroll
  for (int n = 0; n < 2; ++n) {
    const u8* bp = XB + (size_t)(wrow0 + n * 16 + llo) * DIM + lhi * 16;
#pragma unroll
    for (int kb = 0; kb < 4; ++kb) b[n][kb] = *(const i32x4*)(bp + kb * 64);
  }
  // i16 c2 -> LDS (each wave stages its 512-short quarter = 1 KB)
  {
    const short* cp = c2i16 + codeS0 + wid * 512 + lane * 8;
    char* cd = (char*)c2s + wid * 1024;
    __builtin_amdgcn_global_load_lds((gvoid_t*)cp, (lvoid_t*)cd, 16, 0, 0);
  }
  asm volatile("s_waitcnt vmcnt(0)" ::: "memory");  // drain ALL preloads
  __builtin_amdgcn_sched_barrier(0);
  __syncthreads();  // publish c2s -- the ONLY block barrier in this kernel

  // wave-private stage pointers: linear copy of the stored (swizzled) rows;
  // swizzle is resolved at the LDS READ (sl), as verified r15-r19.
  const u8* sp0 = CBb + (size_t)(codeS0 + (lane >> 2)) * DIM + (lane & 3) * 16;
  const u8* sp1 = sp0 + (size_t)16 * DIM;
  const u8* sp2 = sp0 + (size_t)32 * DIM;
  const u8* sp3 = sp0 + (size_t)48 * DIM;
  char* rb = (char*)&ring[wid][0][0];
  const int aoff = llo * 64 + sl * 16;

  int v1[2], v2[2];
#pragma unroll
  for (int n = 0; n < 2; ++n) { v1[n] = 0x7FFFFFFF; v2[n] = 0x7FFFFFFF; }

// stage one 4KB chunk (64 codes x 64B k-group) into ring buf BUF
#define STG(BUF, IMM)                                                          \
  __builtin_amdgcn_global_load_lds((gvoid_t*)(sp0 + (IMM)),                    \
      (lvoid_t*)(rb + (BUF) * 4096 + 0), 16, 0, 0);                            \
  __builtin_amdgcn_global_load_lds((gvoid_t*)(sp1 + (IMM)),                    \
      (lvoid_t*)(rb + (BUF) * 4096 + 1024), 16, 0, 0);                         \
  __builtin_amdgcn_global_load_lds((gvoid_t*)(sp2 + (IMM)),                    \
      (lvoid_t*)(rb + (BUF) * 4096 + 2048), 16, 0, 0);                         \
  __builtin_amdgcn_global_load_lds((gvoid_t*)(sp3 + (IMM)),                    \
      (lvoid_t*)(rb + (BUF) * 4096 + 3072), 16, 0, 0);

// one k-step: wait own ring (vmcnt(4): <=8 outstanding, FIFO retires the
// needed stage), read 4 a-frags, 8 MFMA. KB compile-time.
#define VQMM(KB)                                                               \
  {                                                                            \
    __builtin_amdgcn_sched_barrier(0);                                         \
    asm volatile("s_waitcnt vmcnt(4)" ::: "memory");                           \
    __builtin_amdgcn_sched_barrier(0);                                         \
    const char* asrc = rb + ((KB) & 1) * 4096;                                 \
    i32x4 a0 = *(const i32x4*)(asrc + 0 + aoff);                               \
    i32x4 a1 = *(const i32x4*)(asrc + 1024 + aoff);                            \
    i32x4 a2 = *(const i32x4*)(asrc + 2048 + aoff);                            \
    i32x4 a3 = *(const i32x4*)(asrc + 3072 + aoff);                            \
    _Pragma("unroll")                                                          \
    for (int n = 0; n < 2; ++n) {                                              \
      acc[0][n] = __builtin_amdgcn_mfma_i32_16x16x64_i8(a0, b[n][KB], acc[0][n], 0, 0, 0); \
      acc[1][n] = __builtin_amdgcn_mfma_i32_16x16x64_i8(a1, b[n][KB], acc[1][n], 0, 0, 0); \
      acc[2][n] = __builtin_amdgcn_mfma_i32_16x16x64_i8(a2, b[n][KB], acc[2][n], 0, 0, 0); \
      acc[3][n] = __builtin_amdgcn_mfma_i32_16x16x64_i8(a3, b[n][KB], acc[3][n], 0, 0, 0); \
    }                                                                          \
  }

  STG(0, 0);   // prologue: chunk (ct=0, kb=0) -> buf 0

#pragma unroll 1
  for (int ct = 0; ct < 32; ++ct) {
    i32x4 acc[4][2];
#pragma unroll
    for (int m = 0; m < 4; ++m)
#pragma unroll
      for (int n = 0; n < 2; ++n) acc[m][n] = (i32x4){0, 0, 0, 0};

    STG(1, 64);   VQMM(0)
    STG(0, 128);  VQMM(1)
    STG(1, 192);  VQMM(2)
    sp0 += 16384; sp1 += 16384; sp2 += 16384; sp3 += 16384;  // -> ct+1 base
    STG(0, 0);    VQMM(3)   // stages (ct+1, kb=0); at ct=31: dead in-bounds read

    // epilogue: key = ((c2i - dot) << 13) + code; running top-2 per lane-slice
#pragma unroll
    for (int m = 0; m < 4; ++m) {
      s16x4 cv = *(const s16x4*)((const char*)c2s + ct * 128 + m * 32 + lhi * 8);
      int cbase = codeS0 + ct * 64 + m * 16 + lhi * 4;
      int cvv[4] = {(int)cv[0], (int)cv[1], (int)cv[2], (int)cv[3]};
#pragma unroll
      for (int n = 0; n < 2; ++n) {
#pragma unroll
        for (int r = 0; r < 4; ++r) {
          int diff = cvv[r] - acc[m][n][r];
          int key = (int)(((u32)diff << 13) + (u32)(cbase + r));
          int ov1 = v1[n];
          v1[n] = min(key, ov1);
          v2[n] = min(v2[n], max(key, ov1));
        }
      }
    }
  }
#undef STG
#undef VQMM
  asm volatile("s_waitcnt vmcnt(0)" ::: "memory");  // drain before exit

  // write top-2 per (row, slice); slot = s*4 + lhi; unique writer per slot.
#pragma unroll
  for (int n = 0; n < 2; ++n) {
    int row = wrow0 + n * 16 + llo;
    int slot = s * 4 + lhi;
    partials[(size_t)row * 16 + slot] = make_int2(v1[n], v2[n]);
  }
}

// ---- pick: 32 cands -> top-4 -> exact f32 rescore -> outputs ----
__global__ __launch_bounds__(256)
void vq_pick(const float* __restrict__ x, const float* __restrict__ cb,
             const float* __restrict__ c2g, const int2* __restrict__ partials,
             int* __restrict__ ind, float* __restrict__ out_ind,
             float* __restrict__ out_q, int* __restrict__ cnt,
             float* __restrict__ loss_part) {
  __shared__ float lsm[4];
  int wid = threadIdx.x >> 6, lane = threadIdx.x & 63;
  int row = blockIdx.x * 4 + wid;
  int cv = 0x7FFFFFFF, cv2 = 0x7FFFFFFF;
  if (lane < 16) {
    int2 p = partials[(size_t)row * 16 + lane];
    cv = p.x; cv2 = p.y;
  }
  int cand[4];
#pragma unroll
  for (int rsel = 0; rsel < 4; ++rsel) {
    int bv = cv;
#pragma unroll
    for (int mask = 1; mask < 16; mask <<= 1)
      bv = min(bv, __shfl_xor(bv, mask, 64));
    bv = __shfl(bv, 0, 64);
    cand[rsel] = bv & 8191;
    if (cv == bv) { cv = cv2; cv2 = 0x7FFFFFFF; }
  }
  const float4 xv = *(const float4*)(x + (size_t)row * DIM + lane * 4);
  float4 q0 = *(const float4*)(cb + (size_t)cand[0] * DIM + lane * 4);
  float4 q1 = *(const float4*)(cb + (size_t)cand[1] * DIM + lane * 4);
  float4 q2 = *(const float4*)(cb + (size_t)cand[2] * DIM + lane * 4);
  float4 q3 = *(const float4*)(cb + (size_t)cand[3] * DIM + lane * 4);
  float d0 = xv.x * q0.x + xv.y * q0.y + xv.z * q0.z + xv.w * q0.w;
  float d1 = xv.x * q1.x + xv.y * q1.y + xv.z * q1.z + xv.w * q1.w;
  float d2 = xv.x * q2.x + xv.y * q2.y + xv.z * q2.z + xv.w * q2.w;
  float d3 = xv.x * q3.x + xv.y * q3.y + xv.z * q3.z + xv.w * q3.w;
  float x2 = xv.x * xv.x + xv.y * xv.y + xv.z * xv.z + xv.w * xv.w;
#pragma unroll
  for (int mask = 1; mask < 64; mask <<= 1) {
    d0 += __shfl_xor(d0, mask, 64);
    d1 += __shfl_xor(d1, mask, 64);
    d2 += __shfl_xor(d2, mask, 64);
    d3 += __shfl_xor(d3, mask, 64);
    x2 += __shfl_xor(x2, mask, 64);
  }
  float e0 = fmaf(-2.0f, d0, c2g[cand[0]]);
  float e1 = fmaf(-2.0f, d1, c2g[cand[1]]);
  float e2 = fmaf(-2.0f, d2, c2g[cand[2]]);
  float e3 = fmaf(-2.0f, d3, c2g[cand[3]]);
  float best = e0; int bk = cand[0];
  if (e1 < best || (e1 == best && cand[1] < bk)) { best = e1; bk = cand[1]; }
  if (e2 < best || (e2 == best && cand[2] < bk)) { best = e2; bk = cand[2]; }
  if (e3 < best || (e3 == best && cand[3] < bk)) { best = e3; bk = cand[3]; }
  float4 q = (bk == cand[1]) ? q1 : (bk == cand[2]) ? q2 : (bk == cand[3]) ? q3 : q0;
  *(float4*)(out_q + (size_t)row * DIM + lane * 4) = q;
  if (lane == 0) {
    ind[row] = bk;
    out_ind[row] = (float)bk;
    atomicAdd(cnt + bk, 1);
    lsm[wid] = x2 + best;   // == ||q - x||^2 (exact identity)
  }
  __syncthreads();
  if (threadIdx.x == 0)
    loss_part[blockIdx.x] = lsm[0] + lsm[1] + lsm[2] + lsm[3];
}

// ---- scan: exclusive scan cnt -> offs/woffs; out_cs; reduce loss ----
__global__ __launch_bounds__(1024)
void vq_scan(const int* __restrict__ cnt, int* __restrict__ offs,
             int* __restrict__ woffs, float* __restrict__ out_cs,
             const float* __restrict__ loss_part, float* __restrict__ out_loss) {
  __shared__ int ssum[1024];
  __shared__ float sls[1024];
  int tid = threadIdx.x;
  int c[8], loc[8];
  int s = 0;
#pragma unroll
  for (int j = 0; j < 8; ++j) {
    c[j] = cnt[tid * 8 + j];
    loc[j] = s;
    s += c[j];
  }
  ssum[tid] = s;
  float ls = 0.0f;
#pragma unroll
  for (int j = 0; j < 8; ++j) ls += loss_part[tid * 8 + j];
  sls[tid] = ls;
  __syncthreads();
  for (int off = 1; off < 1024; off <<= 1) {
    int v = (tid >= off) ? ssum[tid - off] : 0;
    __syncthreads();
    ssum[tid] += v;
    __syncthreads();
  }
  int base = (tid > 0) ? ssum[tid - 1] : 0;
#pragma unroll
  for (int j = 0; j < 8; ++j) {
    int o = base + loc[j];
    offs[tid * 8 + j] = o;
    woffs[tid * 8 + j] = o;
    out_cs[tid * 8 + j] = (float)c[j];
  }
  for (int off = 512; off >= 1; off >>= 1) {
    if (tid < off) sls[tid] += sls[tid + off];
    __syncthreads();
  }
  if (tid == 0) *out_loss = sls[0] * (1.0f / 8388608.0f);
}

// ---- scatter: build rowlist grouped by code ----
__global__ __launch_bounds__(256)
void vq_scatter(const int* __restrict__ ind, int* __restrict__ woffs,
                int* __restrict__ rowlist) {
  int row = blockIdx.x * 256 + threadIdx.x;
  int k = ind[row];
  int pos = atomicAdd(woffs + k, 1);
  rowlist[pos] = row;
}

// ---- esum: ONE BLOCK (4 waves) PER CODE; unroll-4 ILP; LDS cross-wave ----
__global__ __launch_bounds__(256)
void vq_esum(const float* __restrict__ x, const int* __restrict__ offs,
             const int* __restrict__ cnt, const int* __restrict__ rowlist,
             float* __restrict__ out_es) {
  __shared__ float4 sred[3][64];
  int k = blockIdx.x;
  int wid = threadIdx.x >> 6, lane = threadIdx.x & 63;
  int start = offs[k], n = cnt[k];
  const int* rl = rowlist + start;
  int jb = (n * wid) >> 2, je = (n * (wid + 1)) >> 2;
  float4 acc = {0.f, 0.f, 0.f, 0.f};
  int j = jb;
  for (; j + 4 <= je; j += 4) {
    int r0 = rl[j], r1 = rl[j + 1], r2 = rl[j + 2], r3 = rl[j + 3];
    float4 v0 = *(const float4*)(x + (size_t)r0 * DIM + lane * 4);
    float4 v1 = *(const float4*)(x + (size_t)r1 * DIM + lane * 4);
    float4 v2 = *(const float4*)(x + (size_t)r2 * DIM + lane * 4);
    float4 v3 = *(const float4*)(x + (size_t)r3 * DIM + lane * 4);
    acc.x += v0.x + v1.x + v2.x + v3.x;
    acc.y += v0.y + v1.y + v2.y + v3.y;
    acc.z += v0.z + v1.z + v2.z + v3.z;
    acc.w += v0.w + v1.w + v2.w + v3.w;
  }
  for (; j < je; ++j) {
    int r = rl[j];
    float4 v = *(const float4*)(x + (size_t)r * DIM + lane * 4);
    acc.x += v.x; acc.y += v.y; acc.z += v.z; acc.w += v.w;
  }
  if (wid > 0) sred[wid - 1][lane] = acc;
  __syncthreads();
  if (wid == 0) {
    float4 a1 = sred[0][lane], a2 = sred[1][lane], a3 = sred[2][lane];
    acc.x += a1.x + a2.x + a3.x;
    acc.y += a1.y + a2.y + a3.y;
    acc.z += a1.z + a2.z + a3.z;
    acc.w += a1.w + a2.w + a3.w;
    *(float4*)(out_es + (size_t)k * DIM + lane * 4) = acc;
  }
}

extern "C" void kernel_launch(void* const* d_in, const int* in_sizes, int n_in,
                              void* d_out, int out_size, void* d_ws,
                              size_t ws_size, hipStream_t stream) {
  const float* x = (const float*)d_in[0];
  const float* cb = (const float*)d_in[1];
  float* out = (float*)d_out;
  float* out_q = out;
  float* out_ind = out + OUT_IND;
  float* out_loss = out + OUT_LOSS;
  float* out_cs = out + OUT_CS;
  float* out_es = out + OUT_ES;

  // Scratch-in-output (r16-19-proven layout):
  u8* Xi8 = (u8*)(out + XI8_OFF);
  u8* Ci8 = (u8*)(out + CI8_OFF);
  int2* partials = (int2*)(out + PART_OFF);

  // ws layout (448 KB; >= 2.21 MB proven available in round 1)
  char* w = (char*)d_ws;
  int* cnt = (int*)w;                              // 32 KB [memset 0]
  int* offs = (int*)(w + (32 << 10));              // 32 KB
  int* woffs = (int*)(w + (64 << 10));             // 32 KB
  float* loss_part = (float*)(w + (96 << 10));     // 32 KB
  int* ind = (int*)(w + (128 << 10));              // 128 KB
  int* rowlist = (int*)(w + (256 << 10));          // 128 KB
  float* c2 = (float*)(w + (384 << 10));           // 32 KB
  short* c2i16 = (short*)(w + (416 << 10));        // 16 KB

  hipMemsetAsync(cnt, 0, KCODES * sizeof(int), stream);
  vq_prep<<<2560, 256, 0, stream>>>(x, cb, Xi8, Ci8, c2, c2i16);
  vq_mfma<<<1024, 256, 0, stream>>>(Xi8, Ci8, c2i16, partials);
  vq_pick<<<BN_TOTAL / 4, 256, 0, stream>>>(x, cb, c2, partials, ind, out_ind,
                                            out_q, cnt, loss_part);
  vq_scan<<<1, 1024, 0, stream>>>(cnt, offs, woffs, out_cs, loss_part, out_loss);
  vq_scatter<<<BN_TOTAL / 256, 256, 0, stream>>>(ind, woffs, rowlist);
  vq_esum<<<KCODES, 256, 0, stream>>>(x, offs, cnt, rowlist, out_es);
}

// Round 22
// 159.055 us; speedup vs baseline: 1.5272x; 1.2212x over previous
//
#include <hip/hip_runtime.h>
#include <hip/hip_bf16.h>
#include <math.h>

#define DIM 256
#define KCODES 8192
#define BN_TOTAL 32768

// d_out flat f32 layout (reference return order)
#define OUT_IND 8388608
#define OUT_LOSS 8421376
#define OUT_CS 8421377
#define OUT_ES 8429569
#define OUT_TOTAL 10526721

// scratch-in-output offsets (f32 units)
#define XI8_OFF 0            // x i8 [32768][256] = 8 MB, dead after mfma
#define CI8_OFF 4194304      // cb i8 [8192][256] (swizzled) = 2 MB, dead after mfma
#define PART_OFF OUT_ES      // partials int2[32768][16] = 4 MB, dead after pick

typedef unsigned short u16;
typedef unsigned char u8;
typedef unsigned int u32;
typedef __attribute__((ext_vector_type(4))) int i32x4;
typedef __attribute__((address_space(1))) const void gvoid_t;
typedef __attribute__((address_space(3))) void lvoid_t;

#define QSCALE (127.0f / 6.0f)
#define INV_2S2 (16129.0f / 72.0f)   // 1/(2*s^2), s = 6/127

// ---- prep: x -> i8 (linear); cb -> i8 (chunk-swizzled) + exact c2 + c2i ----
__global__ __launch_bounds__(256) void vq_prep(const float* __restrict__ x,
                                               const float* __restrict__ cb,
                                               u8* __restrict__ Xi8,
                                               u8* __restrict__ Ci8,
                                               float* __restrict__ c2,
                                               int* __restrict__ c2i) {
  int b = blockIdx.x;
  bool isx = (b < 2048);
  int g = (isx ? b : (b - 2048)) * 256 + threadIdx.x;
  int row = g >> 4;            // x row or code
  int chunk = g & 15;          // 16-element (16B) chunk
  const float* src = (isx ? x : cb) + (size_t)row * DIM + chunk * 16;
  float vv[16];
#pragma unroll
  for (int q = 0; q < 4; ++q) {
    float4 v = *(const float4*)(src + q * 4);
    vv[q * 4 + 0] = v.x; vv[q * 4 + 1] = v.y;
    vv[q * 4 + 2] = v.z; vv[q * 4 + 3] = v.w;
  }
  u32 w[4];
  float s = 0.0f;
#pragma unroll
  for (int q = 0; q < 4; ++q) {
    u32 acc = 0;
#pragma unroll
    for (int e = 0; e < 4; ++e) {
      float v = vv[q * 4 + e];
      s += v * v;
      float vs = fminf(fmaxf(v * QSCALE, -127.0f), 127.0f);
      int iv = (int)rintf(vs);
      acc |= ((u32)(u8)(char)iv) << (8 * e);
    }
    w[q] = acc;
  }
  uint4 pk = {w[0], w[1], w[2], w[3]};
  if (isx) {
    *(uint4*)(Xi8 + (size_t)row * DIM + chunk * 16) = pk;
  } else {
    // swizzle: 16B chunk j of each 64B k-group stored at j ^ ((code>>1)&3)
    int kbg = chunk >> 2;
    int j = chunk & 3;
    int js = j ^ ((row >> 1) & 3);
    *(uint4*)(Ci8 + (size_t)row * DIM + kbg * 64 + js * 16) = pk;
#pragma unroll
    for (int m = 1; m <= 8; m <<= 1) s += __shfl_xor(s, m, 64);  // 16-lane grp
    if (chunk == 0) {
      c2[row] = s;
      c2i[row] = (int)rintf((s - 256.0f) * INV_2S2);
    }
  }
}

// ------------- main: barrier-free wave-async i8 MFMA + int-key top-2 -------
// r19's proven wave-private protocol with RING DEPTH 4 (was 2): the chunk
// read at step cc was staged at step cc-3 (~1000 cy earlier), so vmcnt(12)
// no longer sits on a raw L2 round-trip. Same safety class as r19
// (re-validated deterministic): same-wave produce/consume, FIFO vmcnt
// (16 outstanding after each step's stage; vmcnt(12) retires exactly the
// 4 loads of the chunk being read), preloads drained by vmcnt(0) before
// counting, ZERO non-stage VMEM in the loop (c2i in LDS behind the single
// block barrier), WAR ordered by program order + MFMA's dependence on
// completed ds_reads.
__global__ __launch_bounds__(256, 2)
void vq_mfma(const u8* __restrict__ XB, const u8* __restrict__ CBb,
             const int* __restrict__ c2i, int2* __restrict__ partials) {
  __shared__ __align__(16) u8 ring[4][4][4096];   // wave-private 4-deep rings, 64 KB
  __shared__ __align__(16) int c2s[2048];         // split's c2i, 8 KB
  const int t = threadIdx.x;
  const int wid = t >> 6;
  const int lane = t & 63;
  const int lhi = lane >> 4, llo = lane & 15;
  const int sl = lhi ^ ((llo >> 1) & 3);
  const int rg = blockIdx.x & 127;   // 128 row-groups of 256 rows
  const int s = blockIdx.x >> 7;     // split 0..3
  const int wrow0 = rg * 256 + wid * 64;
  const int codeS0 = s * 2048;

  // preload x fragments: b[n][kb] = 16 i8 at row (wrow0+n*16+llo), K=kb*64+lhi*16
  i32x4 b[4][4];
#pragma unroll
  for (int n = 0; n < 4; ++n) {
    const u8* bp = XB + (size_t)(wrow0 + n * 16 + llo) * DIM + lhi * 16;
#pragma unroll
    for (int kb = 0; kb < 4; ++kb) b[n][kb] = *(const i32x4*)(bp + kb * 64);
  }
  // c2i -> LDS (each wave stages its 512-int quarter)
  {
    const int* cp = c2i + codeS0 + wid * 512 + lane * 4;
    char* cd = (char*)c2s + wid * 2048;
    __builtin_amdgcn_global_load_lds((gvoid_t*)cp, (lvoid_t*)cd, 16, 0, 0);
    __builtin_amdgcn_global_load_lds((gvoid_t*)(cp + 256), (lvoid_t*)(cd + 1024), 16, 0, 0);
  }
  asm volatile("s_waitcnt vmcnt(0)" ::: "memory");  // drain ALL preloads
  __builtin_amdgcn_sched_barrier(0);
  __syncthreads();  // publish c2s -- the ONLY block barrier in this kernel

  // wave-private stage pointers: linear copy of the stored (swizzled) rows;
  // swizzle is resolved at the LDS READ (sl), as verified r15-r21.
  const u8* sp0 = CBb + (size_t)(codeS0 + (lane >> 2)) * DIM + (lane & 3) * 16;
  const u8* sp1 = sp0 + (size_t)16 * DIM;
  const u8* sp2 = sp0 + (size_t)32 * DIM;
  const u8* sp3 = sp0 + (size_t)48 * DIM;
  char* rb = (char*)&ring[wid][0][0];
  const int aoff = llo * 64 + sl * 16;

  int v1[4], v2[4];
#pragma unroll
  for (int n = 0; n < 4; ++n) { v1[n] = 0x7FFFFFFF; v2[n] = 0x7FFFFFFF; }

// stage one 4KB chunk (64 codes x 64B k-group) into ring buf BUF
#define STG(BUF, IMM)                                                          \
  __builtin_amdgcn_global_load_lds((gvoid_t*)(sp0 + (IMM)),                    \
      (lvoid_t*)(rb + (BUF) * 4096 + 0), 16, 0, 0);                            \
  __builtin_amdgcn_global_load_lds((gvoid_t*)(sp1 + (IMM)),                    \
      (lvoid_t*)(rb + (BUF) * 4096 + 1024), 16, 0, 0);                         \
  __builtin_amdgcn_global_load_lds((gvoid_t*)(sp2 + (IMM)),                    \
      (lvoid_t*)(rb + (BUF) * 4096 + 2048), 16, 0, 0);                         \
  __builtin_amdgcn_global_load_lds((gvoid_t*)(sp3 + (IMM)),                    \
      (lvoid_t*)(rb + (BUF) * 4096 + 3072), 16, 0, 0);

// one k-step: wait own ring (vmcnt(12): 16 outstanding after this step's
// stage; FIFO retires exactly the 4 loads of chunk cc), read 4 a-frags,
// 16 MFMA. KB compile-time; buffer = cc&3 = KB.
#define VQMM(KB)                                                               \
  {                                                                            \
    __builtin_amdgcn_sched_barrier(0);                                         \
    asm volatile("s_waitcnt vmcnt(12)" ::: "memory");                          \
    __builtin_amdgcn_sched_barrier(0);                                         \
    const char* asrc = rb + ((KB) & 3) * 4096;                                 \
    i32x4 a0 = *(const i32x4*)(asrc + 0 + aoff);                               \
    i32x4 a1 = *(const i32x4*)(asrc + 1024 + aoff);                            \
    i32x4 a2 = *(const i32x4*)(asrc + 2048 + aoff);                            \
    i32x4 a3 = *(const i32x4*)(asrc + 3072 + aoff);                            \
    _Pragma("unroll")                                                          \
    for (int n = 0; n < 4; ++n) {                                              \
      acc[0][n] = __builtin_amdgcn_mfma_i32_16x16x64_i8(a0, b[n][KB], acc[0][n], 0, 0, 0); \
      acc[1][n] = __builtin_amdgcn_mfma_i32_16x16x64_i8(a1, b[n][KB], acc[1][n], 0, 0, 0); \
      acc[2][n] = __builtin_amdgcn_mfma_i32_16x16x64_i8(a2, b[n][KB], acc[2][n], 0, 0, 0); \
      acc[3][n] = __builtin_amdgcn_mfma_i32_16x16x64_i8(a3, b[n][KB], acc[3][n], 0, 0, 0); \
    }                                                                          \
  }

  // prologue: 3 chunks (12 loads) in flight -> bufs 0,1,2
  STG(0, 0);
  STG(1, 64);
  STG(2, 128);

#pragma unroll 1
  for (int ct = 0; ct < 32; ++ct) {
    i32x4 acc[4][4];
#pragma unroll
    for (int m = 0; m < 4; ++m)
#pragma unroll
      for (int n = 0; n < 4; ++n) acc[m][n] = (i32x4){0, 0, 0, 0};

    STG(3, 192);  VQMM(0)   // stage chunk (ct,3)
    sp0 += 16384; sp1 += 16384; sp2 += 16384; sp3 += 16384;  // -> ct+1 base
    STG(0, 0);    VQMM(1)   // stage (ct+1,0); at ct=31: dead in-bounds read
    STG(1, 64);   VQMM(2)   // stage (ct+1,1); dead at tail
    STG(2, 128);  VQMM(3)   // stage (ct+1,2); dead at tail

    // epilogue: key = ((c2i - dot) << 13) + code; running top-2 per lane-slice
    const int ctb = ct * 256;
#pragma unroll
    for (int m = 0; m < 4; ++m) {
      int4 cv = *(const int4*)((const char*)c2s + ctb + m * 64 + lhi * 16);
      int cbase = codeS0 + ct * 64 + m * 16 + lhi * 4;
      int cvv[4] = {cv.x, cv.y, cv.z, cv.w};
#pragma unroll
      for (int n = 0; n < 4; ++n) {
#pragma unroll
        for (int r = 0; r < 4; ++r) {
          int diff = cvv[r] - acc[m][n][r];
          int key = (int)(((u32)diff << 13) + (u32)(cbase + r));
          int ov1 = v1[n];
          v1[n] = min(key, ov1);
          v2[n] = min(v2[n], max(key, ov1));
        }
      }
    }
  }
#undef STG
#undef VQMM
  asm volatile("s_waitcnt vmcnt(0)" ::: "memory");  // drain before exit

  // write top-2 per (row, slice); slot = s*4 + lhi; unique writer per slot.
#pragma unroll
  for (int n = 0; n < 4; ++n) {
    int row = wrow0 + n * 16 + llo;
    int slot = s * 4 + lhi;
    partials[(size_t)row * 16 + slot] = make_int2(v1[n], v2[n]);
  }
}

// ---- pick: 32 cands -> top-4 -> exact f32 rescore -> outputs ----
__global__ __launch_bounds__(256)
void vq_pick(const float* __restrict__ x, const float* __restrict__ cb,
             const float* __restrict__ c2g, const int2* __restrict__ partials,
             int* __restrict__ ind, float* __restrict__ out_ind,
             float* __restrict__ out_q, int* __restrict__ cnt,
             float* __restrict__ loss_part) {
  __shared__ float lsm[4];
  int wid = threadIdx.x >> 6, lane = threadIdx.x & 63;
  int row = blockIdx.x * 4 + wid;
  int cv = 0x7FFFFFFF, cv2 = 0x7FFFFFFF;
  if (lane < 16) {
    int2 p = partials[(size_t)row * 16 + lane];
    cv = p.x; cv2 = p.y;
  }
  int cand[4];
#pragma unroll
  for (int rsel = 0; rsel < 4; ++rsel) {
    int bv = cv;
#pragma unroll
    for (int mask = 1; mask < 16; mask <<= 1)
      bv = min(bv, __shfl_xor(bv, mask, 64));
    bv = __shfl(bv, 0, 64);
    cand[rsel] = bv & 8191;
    if (cv == bv) { cv = cv2; cv2 = 0x7FFFFFFF; }
  }
  const float4 xv = *(const float4*)(x + (size_t)row * DIM + lane * 4);
  float4 q0 = *(const float4*)(cb + (size_t)cand[0] * DIM + lane * 4);
  float4 q1 = *(const float4*)(cb + (size_t)cand[1] * DIM + lane * 4);
  float4 q2 = *(const float4*)(cb + (size_t)cand[2] * DIM + lane * 4);
  float4 q3 = *(const float4*)(cb + (size_t)cand[3] * DIM + lane * 4);
  float d0 = xv.x * q0.x + xv.y * q0.y + xv.z * q0.z + xv.w * q0.w;
  float d1 = xv.x * q1.x + xv.y * q1.y + xv.z * q1.z + xv.w * q1.w;
  float d2 = xv.x * q2.x + xv.y * q2.y + xv.z * q2.z + xv.w * q2.w;
  float d3 = xv.x * q3.x + xv.y * q3.y + xv.z * q3.z + xv.w * q3.w;
  float x2 = xv.x * xv.x + xv.y * xv.y + xv.z * xv.z + xv.w * xv.w;
#pragma unroll
  for (int mask = 1; mask < 64; mask <<= 1) {
    d0 += __shfl_xor(d0, mask, 64);
    d1 += __shfl_xor(d1, mask, 64);
    d2 += __shfl_xor(d2, mask, 64);
    d3 += __shfl_xor(d3, mask, 64);
    x2 += __shfl_xor(x2, mask, 64);
  }
  float e0 = fmaf(-2.0f, d0, c2g[cand[0]]);
  float e1 = fmaf(-2.0f, d1, c2g[cand[1]]);
  float e2 = fmaf(-2.0f, d2, c2g[cand[2]]);
  float e3 = fmaf(-2.0f, d3, c2g[cand[3]]);
  float best = e0; int bk = cand[0];
  if (e1 < best || (e1 == best && cand[1] < bk)) { best = e1; bk = cand[1]; }
  if (e2 < best || (e2 == best && cand[2] < bk)) { best = e2; bk = cand[2]; }
  if (e3 < best || (e3 == best && cand[3] < bk)) { best = e3; bk = cand[3]; }
  float4 q = (bk == cand[1]) ? q1 : (bk == cand[2]) ? q2 : (bk == cand[3]) ? q3 : q0;
  *(float4*)(out_q + (size_t)row * DIM + lane * 4) = q;
  if (lane == 0) {
    ind[row] = bk;
    out_ind[row] = (float)bk;
    atomicAdd(cnt + bk, 1);
    lsm[wid] = x2 + best;   // == ||q - x||^2 (exact identity)
  }
  __syncthreads();
  if (threadIdx.x == 0)
    loss_part[blockIdx.x] = lsm[0] + lsm[1] + lsm[2] + lsm[3];
}

// ---- scan: exclusive scan cnt -> offs/woffs; out_cs; reduce loss ----
__global__ __launch_bounds__(1024)
void vq_scan(const int* __restrict__ cnt, int* __restrict__ offs,
             int* __restrict__ woffs, float* __restrict__ out_cs,
             const float* __restrict__ loss_part, float* __restrict__ out_loss) {
  __shared__ int ssum[1024];
  __shared__ float sls[1024];
  int tid = threadIdx.x;
  int c[8], loc[8];
  int s = 0;
#pragma unroll
  for (int j = 0; j < 8; ++j) {
    c[j] = cnt[tid * 8 + j];
    loc[j] = s;
    s += c[j];
  }
  ssum[tid] = s;
  float ls = 0.0f;
#pragma unroll
  for (int j = 0; j < 8; ++j) ls += loss_part[tid * 8 + j];
  sls[tid] = ls;
  __syncthreads();
  for (int off = 1; off < 1024; off <<= 1) {
    int v = (tid >= off) ? ssum[tid - off] : 0;
    __syncthreads();
    ssum[tid] += v;
    __syncthreads();
  }
  int base = (tid > 0) ? ssum[tid - 1] : 0;
#pragma unroll
  for (int j = 0; j < 8; ++j) {
    int o = base + loc[j];
    offs[tid * 8 + j] = o;
    woffs[tid * 8 + j] = o;
    out_cs[tid * 8 + j] = (float)c[j];
  }
  for (int off = 512; off >= 1; off >>= 1) {
    if (tid < off) sls[tid] += sls[tid + off];
    __syncthreads();
  }
  if (tid == 0) *out_loss = sls[0] * (1.0f / 8388608.0f);
}

// ---- scatter: build rowlist grouped by code ----
__global__ __launch_bounds__(256)
void vq_scatter(const int* __restrict__ ind, int* __restrict__ woffs,
                int* __restrict__ rowlist) {
  int row = blockIdx.x * 256 + threadIdx.x;
  int k = ind[row];
  int pos = atomicAdd(woffs + k, 1);
  rowlist[pos] = row;
}

// ---- esum: ONE BLOCK (4 waves) PER CODE; unroll-4 ILP; LDS cross-wave ----
__global__ __launch_bounds__(256)
void vq_esum(const float* __restrict__ x, const int* __restrict__ offs,
             const int* __restrict__ cnt, const int* __restrict__ rowlist,
             float* __restrict__ out_es) {
  __shared__ float4 sred[3][64];
  int k = blockIdx.x;
  int wid = threadIdx.x >> 6, lane = threadIdx.x & 63;
  int start = offs[k], n = cnt[k];
  const int* rl = rowlist + start;
  int jb = (n * wid) >> 2, je = (n * (wid + 1)) >> 2;
  float4 acc = {0.f, 0.f, 0.f, 0.f};
  int j = jb;
  for (; j + 4 <= je; j += 4) {
    int r0 = rl[j], r1 = rl[j + 1], r2 = rl[j + 2], r3 = rl[j + 3];
    float4 v0 = *(const float4*)(x + (size_t)r0 * DIM + lane * 4);
    float4 v1 = *(const float4*)(x + (size_t)r1 * DIM + lane * 4);
    float4 v2 = *(const float4*)(x + (size_t)r2 * DIM + lane * 4);
    float4 v3 = *(const float4*)(x + (size_t)r3 * DIM + lane * 4);
    acc.x += v0.x + v1.x + v2.x + v3.x;
    acc.y += v0.y + v1.y + v2.y + v3.y;
    acc.z += v0.z + v1.z + v2.z + v3.z;
    acc.w += v0.w + v1.w + v2.w + v3.w;
  }
  for (; j < je; ++j) {
    int r = rl[j];
    float4 v = *(const float4*)(x + (size_t)r * DIM + lane * 4);
    acc.x += v.x; acc.y += v.y; acc.z += v.z; acc.w += v.w;
  }
  if (wid > 0) sred[wid - 1][lane] = acc;
  __syncthreads();
  if (wid == 0) {
    float4 a1 = sred[0][lane], a2 = sred[1][lane], a3 = sred[2][lane];
    acc.x += a1.x + a2.x + a3.x;
    acc.y += a1.y + a2.y + a3.y;
    acc.z += a1.z + a2.z + a3.z;
    acc.w += a1.w + a2.w + a3.w;
    *(float4*)(out_es + (size_t)k * DIM + lane * 4) = acc;
  }
}

extern "C" void kernel_launch(void* const* d_in, const int* in_sizes, int n_in,
                              void* d_out, int out_size, void* d_ws,
                              size_t ws_size, hipStream_t stream) {
  const float* x = (const float*)d_in[0];
  const float* cb = (const float*)d_in[1];
  float* out = (float*)d_out;
  float* out_q = out;
  float* out_ind = out + OUT_IND;
  float* out_loss = out + OUT_LOSS;
  float* out_cs = out + OUT_CS;
  float* out_es = out + OUT_ES;

  // Scratch-in-output (r16-19-proven layout):
  u8* Xi8 = (u8*)(out + XI8_OFF);
  u8* Ci8 = (u8*)(out + CI8_OFF);
  int2* partials = (int2*)(out + PART_OFF);

  // ws layout (448 KB; >= 2.21 MB proven available in round 1)
  char* w = (char*)d_ws;
  int* cnt = (int*)w;                              // 32 KB [memset 0]
  int* offs = (int*)(w + (32 << 10));              // 32 KB
  int* woffs = (int*)(w + (64 << 10));             // 32 KB
  float* loss_part = (float*)(w + (96 << 10));     // 32 KB
  int* ind = (int*)(w + (128 << 10));              // 128 KB
  int* rowlist = (int*)(w + (256 << 10));          // 128 KB
  float* c2 = (float*)(w + (384 << 10));           // 32 KB
  int* c2i = (int*)(w + (416 << 10));              // 32 KB

  hipMemsetAsync(cnt, 0, KCODES * sizeof(int), stream);
  vq_prep<<<2560, 256, 0, stream>>>(x, cb, Xi8, Ci8, c2, c2i);
  vq_mfma<<<512, 256, 0, stream>>>(Xi8, Ci8, c2i, partials);
  vq_pick<<<BN_TOTAL / 4, 256, 0, stream>>>(x, cb, c2, partials, ind, out_ind,
                                            out_q, cnt, loss_part);
  vq_scan<<<1, 1024, 0, stream>>>(cnt, offs, woffs, out_cs, loss_part, out_loss);
  vq_scatter<<<BN_TOTAL / 256, 256, 0, stream>>>(ind, woffs, rowlist);
  vq_esum<<<KCODES, 256, 0, stream>>>(x, offs, cnt, rowlist, out_es);
}

// Round 23
// 155.411 us; speedup vs baseline: 1.5630x; 1.0234x over previous
//
#include <hip/hip_runtime.h>
#include <hip/hip_bf16.h>
#include <math.h>

#define DIM 256
#define KCODES 8192
#define BN_TOTAL 32768

// d_out flat f32 layout (reference return order)
#define OUT_IND 8388608
#define OUT_LOSS 8421376
#define OUT_CS 8421377
#define OUT_ES 8429569
#define OUT_TOTAL 10526721

// scratch-in-output offsets (f32 units)
#define XI8_OFF 0            // x i8 [32768][256] = 8 MB, dead after mfma
#define CI8_OFF 4194304      // cb i8 [8192][256] (swizzled) = 2 MB, dead after mfma
#define PART_OFF OUT_ES      // partials int2[32768][16] = 4 MB, dead after pick

typedef unsigned short u16;
typedef unsigned char u8;
typedef unsigned int u32;
typedef __attribute__((ext_vector_type(4))) int i32x4;
typedef __attribute__((address_space(1))) const void gvoid_t;
typedef __attribute__((address_space(3))) void lvoid_t;

#define QSCALE (127.0f / 6.0f)
#define INV_2S2 (16129.0f / 72.0f)   // 1/(2*s^2), s = 6/127

// ---- prep: x -> i8 (linear); cb -> i8 (chunk-swizzled) + exact c2 + c2i ----
__global__ __launch_bounds__(256) void vq_prep(const float* __restrict__ x,
                                               const float* __restrict__ cb,
                                               u8* __restrict__ Xi8,
                                               u8* __restrict__ Ci8,
                                               float* __restrict__ c2,
                                               int* __restrict__ c2i) {
  int b = blockIdx.x;
  bool isx = (b < 2048);
  int g = (isx ? b : (b - 2048)) * 256 + threadIdx.x;
  int row = g >> 4;            // x row or code
  int chunk = g & 15;          // 16-element (16B) chunk
  const float* src = (isx ? x : cb) + (size_t)row * DIM + chunk * 16;
  float vv[16];
#pragma unroll
  for (int q = 0; q < 4; ++q) {
    float4 v = *(const float4*)(src + q * 4);
    vv[q * 4 + 0] = v.x; vv[q * 4 + 1] = v.y;
    vv[q * 4 + 2] = v.z; vv[q * 4 + 3] = v.w;
  }
  u32 w[4];
  float s = 0.0f;
#pragma unroll
  for (int q = 0; q < 4; ++q) {
    u32 acc = 0;
#pragma unroll
    for (int e = 0; e < 4; ++e) {
      float v = vv[q * 4 + e];
      s += v * v;
      float vs = fminf(fmaxf(v * QSCALE, -127.0f), 127.0f);
      int iv = (int)rintf(vs);
      acc |= ((u32)(u8)(char)iv) << (8 * e);
    }
    w[q] = acc;
  }
  uint4 pk = {w[0], w[1], w[2], w[3]};
  if (isx) {
    *(uint4*)(Xi8 + (size_t)row * DIM + chunk * 16) = pk;
  } else {
    // swizzle: 16B chunk j of each 64B k-group stored at j ^ ((code>>1)&3)
    int kbg = chunk >> 2;
    int j = chunk & 3;
    int js = j ^ ((row >> 1) & 3);
    *(uint4*)(Ci8 + (size_t)row * DIM + kbg * 64 + js * 16) = pk;
#pragma unroll
    for (int m = 1; m <= 8; m <<= 1) s += __shfl_xor(s, m, 64);  // 16-lane grp
    if (chunk == 0) {
      c2[row] = s;
      c2i[row] = (int)rintf((s - 256.0f) * INV_2S2);
    }
  }
}

// ------------- main: barrier-free wave-async i8 MFMA + int-key top-2 -------
// r19's proven protocol (re-validated deterministic), with the top-2 update
// compressed to min + v_med3_i32: v2 = median(key, v1_old, v2) is exactly
// min(v2, max(key, v1_old)) under the invariant v1 <= v2 (induction from the
// INT_MAX init). 4 VALU ops/element instead of 5 -- the kernel is
// issue-bound (VALUBusy 53% + MfmaUtil 30% at 2 waves/SIMD).
__global__ __launch_bounds__(256, 2)
void vq_mfma(const u8* __restrict__ XB, const u8* __restrict__ CBb,
             const int* __restrict__ c2i, int2* __restrict__ partials) {
  __shared__ __align__(16) u8 ring[4][2][4096];   // wave-private rings, 32 KB
  __shared__ __align__(16) int c2s[2048];         // split's c2i, 8 KB
  const int t = threadIdx.x;
  const int wid = t >> 6;
  const int lane = t & 63;
  const int lhi = lane >> 4, llo = lane & 15;
  const int sl = lhi ^ ((llo >> 1) & 3);
  const int rg = blockIdx.x & 127;   // 128 row-groups of 256 rows
  const int s = blockIdx.x >> 7;     // split 0..3
  const int wrow0 = rg * 256 + wid * 64;
  const int codeS0 = s * 2048;

  // preload x fragments: b[n][kb] = 16 i8 at row (wrow0+n*16+llo), K=kb*64+lhi*16
  i32x4 b[4][4];
#pragma unroll
  for (int n = 0; n < 4; ++n) {
    const u8* bp = XB + (size_t)(wrow0 + n * 16 + llo) * DIM + lhi * 16;
#pragma unroll
    for (int kb = 0; kb < 4; ++kb) b[n][kb] = *(const i32x4*)(bp + kb * 64);
  }
  // c2i -> LDS (each wave stages its 512-int quarter)
  {
    const int* cp = c2i + codeS0 + wid * 512 + lane * 4;
    char* cd = (char*)c2s + wid * 2048;
    __builtin_amdgcn_global_load_lds((gvoid_t*)cp, (lvoid_t*)cd, 16, 0, 0);
    __builtin_amdgcn_global_load_lds((gvoid_t*)(cp + 256), (lvoid_t*)(cd + 1024), 16, 0, 0);
  }
  asm volatile("s_waitcnt vmcnt(0)" ::: "memory");  // drain ALL preloads
  __builtin_amdgcn_sched_barrier(0);
  __syncthreads();  // publish c2s -- the ONLY block barrier in this kernel

  // wave-private stage pointers: linear copy of the stored (swizzled) rows;
  // swizzle is resolved at the LDS READ (sl), as verified r15-r22.
  const u8* sp0 = CBb + (size_t)(codeS0 + (lane >> 2)) * DIM + (lane & 3) * 16;
  const u8* sp1 = sp0 + (size_t)16 * DIM;
  const u8* sp2 = sp0 + (size_t)32 * DIM;
  const u8* sp3 = sp0 + (size_t)48 * DIM;
  char* rb = (char*)&ring[wid][0][0];
  const int aoff = llo * 64 + sl * 16;

  int v1[4], v2[4];
#pragma unroll
  for (int n = 0; n < 4; ++n) { v1[n] = 0x7FFFFFFF; v2[n] = 0x7FFFFFFF; }

// stage one 4KB chunk (64 codes x 64B k-group) into ring buf BUF
#define STG(BUF, IMM)                                                          \
  __builtin_amdgcn_global_load_lds((gvoid_t*)(sp0 + (IMM)),                    \
      (lvoid_t*)(rb + (BUF) * 4096 + 0), 16, 0, 0);                            \
  __builtin_amdgcn_global_load_lds((gvoid_t*)(sp1 + (IMM)),                    \
      (lvoid_t*)(rb + (BUF) * 4096 + 1024), 16, 0, 0);                         \
  __builtin_amdgcn_global_load_lds((gvoid_t*)(sp2 + (IMM)),                    \
      (lvoid_t*)(rb + (BUF) * 4096 + 2048), 16, 0, 0);                         \
  __builtin_amdgcn_global_load_lds((gvoid_t*)(sp3 + (IMM)),                    \
      (lvoid_t*)(rb + (BUF) * 4096 + 3072), 16, 0, 0);

// one k-step: wait own ring (vmcnt(4): <=8 outstanding, FIFO retires the
// needed stage), read 4 a-frags, 16 MFMA. KB compile-time.
#define VQMM(KB)                                                               \
  {                                                                            \
    __builtin_amdgcn_sched_barrier(0);                                         \
    asm volatile("s_waitcnt vmcnt(4)" ::: "memory");                           \
    __builtin_amdgcn_sched_barrier(0);                                         \
    const char* asrc = rb + ((KB) & 1) * 4096;                                 \
    i32x4 a0 = *(const i32x4*)(asrc + 0 + aoff);                               \
    i32x4 a1 = *(const i32x4*)(asrc + 1024 + aoff);                            \
    i32x4 a2 = *(const i32x4*)(asrc + 2048 + aoff);                            \
    i32x4 a3 = *(const i32x4*)(asrc + 3072 + aoff);                            \
    _Pragma("unroll")                                                          \
    for (int n = 0; n < 4; ++n) {                                              \
      acc[0][n] = __builtin_amdgcn_mfma_i32_16x16x64_i8(a0, b[n][KB], acc[0][n], 0, 0, 0); \
      acc[1][n] = __builtin_amdgcn_mfma_i32_16x16x64_i8(a1, b[n][KB], acc[1][n], 0, 0, 0); \
      acc[2][n] = __builtin_amdgcn_mfma_i32_16x16x64_i8(a2, b[n][KB], acc[2][n], 0, 0, 0); \
      acc[3][n] = __builtin_amdgcn_mfma_i32_16x16x64_i8(a3, b[n][KB], acc[3][n], 0, 0, 0); \
    }                                                                          \
  }

  STG(0, 0);   // prologue: chunk (ct=0, kb=0) -> buf 0

#pragma unroll 1
  for (int ct = 0; ct < 32; ++ct) {
    i32x4 acc[4][4];
#pragma unroll
    for (int m = 0; m < 4; ++m)
#pragma unroll
      for (int n = 0; n < 4; ++n) acc[m][n] = (i32x4){0, 0, 0, 0};

    STG(1, 64);   VQMM(0)
    STG(0, 128);  VQMM(1)
    STG(1, 192);  VQMM(2)
    sp0 += 16384; sp1 += 16384; sp2 += 16384; sp3 += 16384;  // -> ct+1 base
    STG(0, 0);    VQMM(3)   // stages (ct+1, kb=0); at ct=31: dead in-bounds read

    // epilogue: key = ((c2i - dot) << 13) + code; top-2 via min + v_med3_i32
    const int ctb = ct * 256;
#pragma unroll
    for (int m = 0; m < 4; ++m) {
      int4 cv = *(const int4*)((const char*)c2s + ctb + m * 64 + lhi * 16);
      int cbase = codeS0 + ct * 64 + m * 16 + lhi * 4;
      int cvv[4] = {cv.x, cv.y, cv.z, cv.w};
#pragma unroll
      for (int n = 0; n < 4; ++n) {
#pragma unroll
        for (int r = 0; r < 4; ++r) {
          int diff = cvv[r] - acc[m][n][r];
          int key = (int)(((u32)diff << 13) + (u32)(cbase + r));
          int ov1 = v1[n];
          int nv2;
          asm("v_med3_i32 %0, %1, %2, %3"
              : "=v"(nv2) : "v"(key), "v"(ov1), "v"(v2[n]));
          v2[n] = nv2;
          v1[n] = min(key, ov1);
        }
      }
    }
  }
#undef STG
#undef VQMM
  asm volatile("s_waitcnt vmcnt(0)" ::: "memory");  // drain before exit

  // write top-2 per (row, slice); slot = s*4 + lhi; unique writer per slot.
#pragma unroll
  for (int n = 0; n < 4; ++n) {
    int row = wrow0 + n * 16 + llo;
    int slot = s * 4 + lhi;
    partials[(size_t)row * 16 + slot] = make_int2(v1[n], v2[n]);
  }
}

// ---- pick: 32 cands -> top-4 -> exact f32 rescore -> outputs ----
__global__ __launch_bounds__(256)
void vq_pick(const float* __restrict__ x, const float* __restrict__ cb,
             const float* __restrict__ c2g, const int2* __restrict__ partials,
             int* __restrict__ ind, float* __restrict__ out_ind,
             float* __restrict__ out_q, int* __restrict__ cnt,
             float* __restrict__ loss_part) {
  __shared__ float lsm[4];
  int wid = threadIdx.x >> 6, lane = threadIdx.x & 63;
  int row = blockIdx.x * 4 + wid;
  int cv = 0x7FFFFFFF, cv2 = 0x7FFFFFFF;
  if (lane < 16) {
    int2 p = partials[(size_t)row * 16 + lane];
    cv = p.x; cv2 = p.y;
  }
  int cand[4];
#pragma unroll
  for (int rsel = 0; rsel < 4; ++rsel) {
    int bv = cv;
#pragma unroll
    for (int mask = 1; mask < 16; mask <<= 1)
      bv = min(bv, __shfl_xor(bv, mask, 64));
    bv = __shfl(bv, 0, 64);
    cand[rsel] = bv & 8191;
    if (cv == bv) { cv = cv2; cv2 = 0x7FFFFFFF; }
  }
  const float4 xv = *(const float4*)(x + (size_t)row * DIM + lane * 4);
  float4 q0 = *(const float4*)(cb + (size_t)cand[0] * DIM + lane * 4);
  float4 q1 = *(const float4*)(cb + (size_t)cand[1] * DIM + lane * 4);
  float4 q2 = *(const float4*)(cb + (size_t)cand[2] * DIM + lane * 4);
  float4 q3 = *(const float4*)(cb + (size_t)cand[3] * DIM + lane * 4);
  float d0 = xv.x * q0.x + xv.y * q0.y + xv.z * q0.z + xv.w * q0.w;
  float d1 = xv.x * q1.x + xv.y * q1.y + xv.z * q1.z + xv.w * q1.w;
  float d2 = xv.x * q2.x + xv.y * q2.y + xv.z * q2.z + xv.w * q2.w;
  float d3 = xv.x * q3.x + xv.y * q3.y + xv.z * q3.z + xv.w * q3.w;
  float x2 = xv.x * xv.x + xv.y * xv.y + xv.z * xv.z + xv.w * xv.w;
#pragma unroll
  for (int mask = 1; mask < 64; mask <<= 1) {
    d0 += __shfl_xor(d0, mask, 64);
    d1 += __shfl_xor(d1, mask, 64);
    d2 += __shfl_xor(d2, mask, 64);
    d3 += __shfl_xor(d3, mask, 64);
    x2 += __shfl_xor(x2, mask, 64);
  }
  float e0 = fmaf(-2.0f, d0, c2g[cand[0]]);
  float e1 = fmaf(-2.0f, d1, c2g[cand[1]]);
  float e2 = fmaf(-2.0f, d2, c2g[cand[2]]);
  float e3 = fmaf(-2.0f, d3, c2g[cand[3]]);
  float best = e0; int bk = cand[0];
  if (e1 < best || (e1 == best && cand[1] < bk)) { best = e1; bk = cand[1]; }
  if (e2 < best || (e2 == best && cand[2] < bk)) { best = e2; bk = cand[2]; }
  if (e3 < best || (e3 == best && cand[3] < bk)) { best = e3; bk = cand[3]; }
  float4 q = (bk == cand[1]) ? q1 : (bk == cand[2]) ? q2 : (bk == cand[3]) ? q3 : q0;
  *(float4*)(out_q + (size_t)row * DIM + lane * 4) = q;
  if (lane == 0) {
    ind[row] = bk;
    out_ind[row] = (float)bk;
    atomicAdd(cnt + bk, 1);
    lsm[wid] = x2 + best;   // == ||q - x||^2 (exact identity)
  }
  __syncthreads();
  if (threadIdx.x == 0)
    loss_part[blockIdx.x] = lsm[0] + lsm[1] + lsm[2] + lsm[3];
}

// ---- scan: exclusive scan cnt -> offs/woffs; out_cs; reduce loss ----
__global__ __launch_bounds__(1024)
void vq_scan(const int* __restrict__ cnt, int* __restrict__ offs,
             int* __restrict__ woffs, float* __restrict__ out_cs,
             const float* __restrict__ loss_part, float* __restrict__ out_loss) {
  __shared__ int ssum[1024];
  __shared__ float sls[1024];
  int tid = threadIdx.x;
  int c[8], loc[8];
  int s = 0;
#pragma unroll
  for (int j = 0; j < 8; ++j) {
    c[j] = cnt[tid * 8 + j];
    loc[j] = s;
    s += c[j];
  }
  ssum[tid] = s;
  float ls = 0.0f;
#pragma unroll
  for (int j = 0; j < 8; ++j) ls += loss_part[tid * 8 + j];
  sls[tid] = ls;
  __syncthreads();
  for (int off = 1; off < 1024; off <<= 1) {
    int v = (tid >= off) ? ssum[tid - off] : 0;
    __syncthreads();
    ssum[tid] += v;
    __syncthreads();
  }
  int base = (tid > 0) ? ssum[tid - 1] : 0;
#pragma unroll
  for (int j = 0; j < 8; ++j) {
    int o = base + loc[j];
    offs[tid * 8 + j] = o;
    woffs[tid * 8 + j] = o;
    out_cs[tid * 8 + j] = (float)c[j];
  }
  for (int off = 512; off >= 1; off >>= 1) {
    if (tid < off) sls[tid] += sls[tid + off];
    __syncthreads();
  }
  if (tid == 0) *out_loss = sls[0] * (1.0f / 8388608.0f);
}

// ---- scatter: build rowlist grouped by code ----
__global__ __launch_bounds__(256)
void vq_scatter(const int* __restrict__ ind, int* __restrict__ woffs,
                int* __restrict__ rowlist) {
  int row = blockIdx.x * 256 + threadIdx.x;
  int k = ind[row];
  int pos = atomicAdd(woffs + k, 1);
  rowlist[pos] = row;
}

// ---- esum: ONE BLOCK (4 waves) PER CODE; unroll-4 ILP; LDS cross-wave ----
__global__ __launch_bounds__(256)
void vq_esum(const float* __restrict__ x, const int* __restrict__ offs,
             const int* __restrict__ cnt, const int* __restrict__ rowlist,
             float* __restrict__ out_es) {
  __shared__ float4 sred[3][64];
  int k = blockIdx.x;
  int wid = threadIdx.x >> 6, lane = threadIdx.x & 63;
  int start = offs[k], n = cnt[k];
  const int* rl = rowlist + start;
  int jb = (n * wid) >> 2, je = (n * (wid + 1)) >> 2;
  float4 acc = {0.f, 0.f, 0.f, 0.f};
  int j = jb;
  for (; j + 4 <= je; j += 4) {
    int r0 = rl[j], r1 = rl[j + 1], r2 = rl[j + 2], r3 = rl[j + 3];
    float4 v0 = *(const float4*)(x + (size_t)r0 * DIM + lane * 4);
    float4 v1 = *(const float4*)(x + (size_t)r1 * DIM + lane * 4);
    float4 v2 = *(const float4*)(x + (size_t)r2 * DIM + lane * 4);
    float4 v3 = *(const float4*)(x + (size_t)r3 * DIM + lane * 4);
    acc.x += v0.x + v1.x + v2.x + v3.x;
    acc.y += v0.y + v1.y + v2.y + v3.y;
    acc.z += v0.z + v1.z + v2.z + v3.z;
    acc.w += v0.w + v1.w + v2.w + v3.w;
  }
  for (; j < je; ++j) {
    int r = rl[j];
    float4 v = *(const float4*)(x + (size_t)r * DIM + lane * 4);
    acc.x += v.x; acc.y += v.y; acc.z += v.z; acc.w += v.w;
  }
  if (wid > 0) sred[wid - 1][lane] = acc;
  __syncthreads();
  if (wid == 0) {
    float4 a1 = sred[0][lane], a2 = sred[1][lane], a3 = sred[2][lane];
    acc.x += a1.x + a2.x + a3.x;
    acc.y += a1.y + a2.y + a3.y;
    acc.z += a1.z + a2.z + a3.z;
    acc.w += a1.w + a2.w + a3.w;
    *(float4*)(out_es + (size_t)k * DIM + lane * 4) = acc;
  }
}

extern "C" void kernel_launch(void* const* d_in, const int* in_sizes, int n_in,
                              void* d_out, int out_size, void* d_ws,
                              size_t ws_size, hipStream_t stream) {
  const float* x = (const float*)d_in[0];
  const float* cb = (const float*)d_in[1];
  float* out = (float*)d_out;
  float* out_q = out;
  float* out_ind = out + OUT_IND;
  float* out_loss = out + OUT_LOSS;
  float* out_cs = out + OUT_CS;
  float* out_es = out + OUT_ES;

  // Scratch-in-output (r16-19-proven layout):
  u8* Xi8 = (u8*)(out + XI8_OFF);
  u8* Ci8 = (u8*)(out + CI8_OFF);
  int2* partials = (int2*)(out + PART_OFF);

  // ws layout (448 KB; >= 2.21 MB proven available in round 1)
  char* w = (char*)d_ws;
  int* cnt = (int*)w;                              // 32 KB [memset 0]
  int* offs = (int*)(w + (32 << 10));              // 32 KB
  int* woffs = (int*)(w + (64 << 10));             // 32 KB
  float* loss_part = (float*)(w + (96 << 10));     // 32 KB
  int* ind = (int*)(w + (128 << 10));              // 128 KB
  int* rowlist = (int*)(w + (256 << 10));          // 128 KB
  float* c2 = (float*)(w + (384 << 10));           // 32 KB
  int* c2i = (int*)(w + (416 << 10));              // 32 KB

  hipMemsetAsync(cnt, 0, KCODES * sizeof(int), stream);
  vq_prep<<<2560, 256, 0, stream>>>(x, cb, Xi8, Ci8, c2, c2i);
  vq_mfma<<<512, 256, 0, stream>>>(Xi8, Ci8, c2i, partials);
  vq_pick<<<BN_TOTAL / 4, 256, 0, stream>>>(x, cb, c2, partials, ind, out_ind,
                                            out_q, cnt, loss_part);
  vq_scan<<<1, 1024, 0, stream>>>(cnt, offs, woffs, out_cs, loss_part, out_loss);
  vq_scatter<<<BN_TOTAL / 256, 256, 0, stream>>>(ind, woffs, rowlist);
  vq_esum<<<KCODES, 256, 0, stream>>>(x, offs, cnt, rowlist, out_es);
}

// Round 25
// 152.062 us; speedup vs baseline: 1.5974x; 1.0220x over previous
//
#include <hip/hip_runtime.h>
#include <hip/hip_bf16.h>
#include <math.h>

#define DIM 256
#define KCODES 8192
#define BN_TOTAL 32768

// d_out flat f32 layout (reference return order)
#define OUT_IND 8388608
#define OUT_LOSS 8421376
#define OUT_CS 8421377
#define OUT_ES 8429569
#define OUT_TOTAL 10526721

// scratch-in-output offsets (f32 units)
#define XI8_OFF 0            // x i8 [32768][256] = 8 MB, dead after mfma
#define CI8_OFF 4194304      // cb i8 [8192][256] (swizzled) = 2 MB, dead after mfma
#define PART_OFF OUT_ES      // partials int2[32768][16] = 4 MB, dead after pick

typedef unsigned short u16;
typedef unsigned char u8;
typedef unsigned int u32;
typedef __attribute__((ext_vector_type(4))) int i32x4;
typedef __attribute__((address_space(1))) const void gvoid_t;
typedef __attribute__((address_space(3))) void lvoid_t;

#define QSCALE (127.0f / 6.0f)
#define INV_2S2 (16129.0f / 72.0f)   // 1/(2*s^2), s = 6/127

// ---- prep: x -> i8; cb -> i8 (chunk-swizzled) + exact c2 + c2i; zero cnt ----
__global__ __launch_bounds__(256) void vq_prep(const float* __restrict__ x,
                                               const float* __restrict__ cb,
                                               u8* __restrict__ Xi8,
                                               u8* __restrict__ Ci8,
                                               float* __restrict__ c2,
                                               int* __restrict__ c2i,
                                               int* __restrict__ cnt) {
  int b = blockIdx.x;
  if (b < 32) cnt[b * 256 + threadIdx.x] = 0;   // fused memset (8192 ints)
  bool isx = (b < 2048);
  int g = (isx ? b : (b - 2048)) * 256 + threadIdx.x;
  int row = g >> 4;            // x row or code
  int chunk = g & 15;          // 16-element (16B) chunk
  const float* src = (isx ? x : cb) + (size_t)row * DIM + chunk * 16;
  float vv[16];
#pragma unroll
  for (int q = 0; q < 4; ++q) {
    float4 v = *(const float4*)(src + q * 4);
    vv[q * 4 + 0] = v.x; vv[q * 4 + 1] = v.y;
    vv[q * 4 + 2] = v.z; vv[q * 4 + 3] = v.w;
  }
  u32 w[4];
  float s = 0.0f;
#pragma unroll
  for (int q = 0; q < 4; ++q) {
    u32 acc = 0;
#pragma unroll
    for (int e = 0; e < 4; ++e) {
      float v = vv[q * 4 + e];
      s += v * v;
      float vs = fminf(fmaxf(v * QSCALE, -127.0f), 127.0f);
      int iv = (int)rintf(vs);
      acc |= ((u32)(u8)(char)iv) << (8 * e);
    }
    w[q] = acc;
  }
  uint4 pk = {w[0], w[1], w[2], w[3]};
  if (isx) {
    *(uint4*)(Xi8 + (size_t)row * DIM + chunk * 16) = pk;
  } else {
    // swizzle: 16B chunk j of each 64B k-group stored at j ^ ((code>>1)&3)
    int kbg = chunk >> 2;
    int j = chunk & 3;
    int js = j ^ ((row >> 1) & 3);
    *(uint4*)(Ci8 + (size_t)row * DIM + kbg * 64 + js * 16) = pk;
#pragma unroll
    for (int m = 1; m <= 8; m <<= 1) s += __shfl_xor(s, m, 64);  // 16-lane grp
    if (chunk == 0) {
      c2[row] = s;
      c2i[row] = (int)rintf((s - 256.0f) * INV_2S2);
    }
  }
}

// ------------- main: barrier-free wave-async i8 MFMA + int-key top-2 -------
// r19/r23's proven protocol (re-validated deterministic): top-2 per
// lane-slice is the SAFETY MINIMUM -- when global rank-1 and rank-2 share a
// slice (P=1/16) and the i8 approx flips them (P~4%), both must stay in the
// candidate set for the exact f32 rescore to recover (r24's top-1 cut broke
// exactly this). Update = min + v_med3_i32 (valid under invariant v1<=v2).
__global__ __launch_bounds__(256, 2)
void vq_mfma(const u8* __restrict__ XB, const u8* __restrict__ CBb,
             const int* __restrict__ c2i, int2* __restrict__ partials) {
  __shared__ __align__(16) u8 ring[4][2][4096];   // wave-private rings, 32 KB
  __shared__ __align__(16) int c2s[2048];         // split's c2i, 8 KB
  const int t = threadIdx.x;
  const int wid = t >> 6;
  const int lane = t & 63;
  const int lhi = lane >> 4, llo = lane & 15;
  const int sl = lhi ^ ((llo >> 1) & 3);
  const int rg = blockIdx.x & 127;   // 128 row-groups of 256 rows
  const int s = blockIdx.x >> 7;     // split 0..3
  const int wrow0 = rg * 256 + wid * 64;
  const int codeS0 = s * 2048;

  // preload x fragments: b[n][kb] = 16 i8 at row (wrow0+n*16+llo), K=kb*64+lhi*16
  i32x4 b[4][4];
#pragma unroll
  for (int n = 0; n < 4; ++n) {
    const u8* bp = XB + (size_t)(wrow0 + n * 16 + llo) * DIM + lhi * 16;
#pragma unroll
    for (int kb = 0; kb < 4; ++kb) b[n][kb] = *(const i32x4*)(bp + kb * 64);
  }
  // c2i -> LDS (each wave stages its 512-int quarter)
  {
    const int* cp = c2i + codeS0 + wid * 512 + lane * 4;
    char* cd = (char*)c2s + wid * 2048;
    __builtin_amdgcn_global_load_lds((gvoid_t*)cp, (lvoid_t*)cd, 16, 0, 0);
    __builtin_amdgcn_global_load_lds((gvoid_t*)(cp + 256), (lvoid_t*)(cd + 1024), 16, 0, 0);
  }
  asm volatile("s_waitcnt vmcnt(0)" ::: "memory");  // drain ALL preloads
  __builtin_amdgcn_sched_barrier(0);
  __syncthreads();  // publish c2s -- the ONLY block barrier in this kernel

  // wave-private stage pointers: linear copy of the stored (swizzled) rows;
  // swizzle is resolved at the LDS READ (sl), as verified r15-r23.
  const u8* sp0 = CBb + (size_t)(codeS0 + (lane >> 2)) * DIM + (lane & 3) * 16;
  const u8* sp1 = sp0 + (size_t)16 * DIM;
  const u8* sp2 = sp0 + (size_t)32 * DIM;
  const u8* sp3 = sp0 + (size_t)48 * DIM;
  char* rb = (char*)&ring[wid][0][0];
  const int aoff = llo * 64 + sl * 16;

  int v1[4], v2[4];
#pragma unroll
  for (int n = 0; n < 4; ++n) { v1[n] = 0x7FFFFFFF; v2[n] = 0x7FFFFFFF; }

// stage one 4KB chunk (64 codes x 64B k-group) into ring buf BUF
#define STG(BUF, IMM)                                                          \
  __builtin_amdgcn_global_load_lds((gvoid_t*)(sp0 + (IMM)),                    \
      (lvoid_t*)(rb + (BUF) * 4096 + 0), 16, 0, 0);                            \
  __builtin_amdgcn_global_load_lds((gvoid_t*)(sp1 + (IMM)),                    \
      (lvoid_t*)(rb + (BUF) * 4096 + 1024), 16, 0, 0);                         \
  __builtin_amdgcn_global_load_lds((gvoid_t*)(sp2 + (IMM)),                    \
      (lvoid_t*)(rb + (BUF) * 4096 + 2048), 16, 0, 0);                         \
  __builtin_amdgcn_global_load_lds((gvoid_t*)(sp3 + (IMM)),                    \
      (lvoid_t*)(rb + (BUF) * 4096 + 3072), 16, 0, 0);

// one k-step: wait own ring (vmcnt(4): <=8 outstanding, FIFO retires the
// needed stage), read 4 a-frags, 16 MFMA. KB compile-time.
#define VQMM(KB)                                                               \
  {                                                                            \
    __builtin_amdgcn_sched_barrier(0);                                         \
    asm volatile("s_waitcnt vmcnt(4)" ::: "memory");                           \
    __builtin_amdgcn_sched_barrier(0);                                         \
    const char* asrc = rb + ((KB) & 1) * 4096;                                 \
    i32x4 a0 = *(const i32x4*)(asrc + 0 + aoff);                               \
    i32x4 a1 = *(const i32x4*)(asrc + 1024 + aoff);                            \
    i32x4 a2 = *(const i32x4*)(asrc + 2048 + aoff);                            \
    i32x4 a3 = *(const i32x4*)(asrc + 3072 + aoff);                            \
    _Pragma("unroll")                                                          \
    for (int n = 0; n < 4; ++n) {                                              \
      acc[0][n] = __builtin_amdgcn_mfma_i32_16x16x64_i8(a0, b[n][KB], acc[0][n], 0, 0, 0); \
      acc[1][n] = __builtin_amdgcn_mfma_i32_16x16x64_i8(a1, b[n][KB], acc[1][n], 0, 0, 0); \
      acc[2][n] = __builtin_amdgcn_mfma_i32_16x16x64_i8(a2, b[n][KB], acc[2][n], 0, 0, 0); \
      acc[3][n] = __builtin_amdgcn_mfma_i32_16x16x64_i8(a3, b[n][KB], acc[3][n], 0, 0, 0); \
    }                                                                          \
  }

  STG(0, 0);   // prologue: chunk (ct=0, kb=0) -> buf 0

#pragma unroll 1
  for (int ct = 0; ct < 32; ++ct) {
    i32x4 acc[4][4];
#pragma unroll
    for (int m = 0; m < 4; ++m)
#pragma unroll
      for (int n = 0; n < 4; ++n) acc[m][n] = (i32x4){0, 0, 0, 0};

    STG(1, 64);   VQMM(0)
    STG(0, 128);  VQMM(1)
    STG(1, 192);  VQMM(2)
    sp0 += 16384; sp1 += 16384; sp2 += 16384; sp3 += 16384;  // -> ct+1 base
    STG(0, 0);    VQMM(3)   // stages (ct+1, kb=0); at ct=31: dead in-bounds read

    // epilogue: key = ((c2i - dot) << 13) + code; top-2 via min + v_med3_i32
    const int ctb = ct * 256;
#pragma unroll
    for (int m = 0; m < 4; ++m) {
      int4 cv = *(const int4*)((const char*)c2s + ctb + m * 64 + lhi * 16);
      int cbase = codeS0 + ct * 64 + m * 16 + lhi * 4;
      int cvv[4] = {cv.x, cv.y, cv.z, cv.w};
#pragma unroll
      for (int n = 0; n < 4; ++n) {
#pragma unroll
        for (int r = 0; r < 4; ++r) {
          int diff = cvv[r] - acc[m][n][r];
          int key = (int)(((u32)diff << 13) + (u32)(cbase + r));
          int ov1 = v1[n];
          int nv2;
          asm("v_med3_i32 %0, %1, %2, %3"
              : "=v"(nv2) : "v"(key), "v"(ov1), "v"(v2[n]));
          v2[n] = nv2;
          v1[n] = min(key, ov1);
        }
      }
    }
  }
#undef STG
#undef VQMM
  asm volatile("s_waitcnt vmcnt(0)" ::: "memory");  // drain before exit

  // write top-2 per (row, slice); slot = s*4 + lhi; unique writer per slot.
#pragma unroll
  for (int n = 0; n < 4; ++n) {
    int row = wrow0 + n * 16 + llo;
    int slot = s * 4 + lhi;
    partials[(size_t)row * 16 + slot] = make_int2(v1[n], v2[n]);
  }
}

// ---- pick: 32 cands -> top-4 -> exact f32 rescore -> outputs ----
__global__ __launch_bounds__(256)
void vq_pick(const float* __restrict__ x, const float* __restrict__ cb,
             const float* __restrict__ c2g, const int2* __restrict__ partials,
             int* __restrict__ ind, float* __restrict__ out_ind,
             float* __restrict__ out_q, int* __restrict__ cnt,
             float* __restrict__ loss_part) {
  __shared__ float lsm[4];
  int wid = threadIdx.x >> 6, lane = threadIdx.x & 63;
  int row = blockIdx.x * 4 + wid;
  int cv = 0x7FFFFFFF, cv2 = 0x7FFFFFFF;
  if (lane < 16) {
    int2 p = partials[(size_t)row * 16 + lane];
    cv = p.x; cv2 = p.y;
  }
  int cand[4];
#pragma unroll
  for (int rsel = 0; rsel < 4; ++rsel) {
    int bv = cv;
#pragma unroll
    for (int mask = 1; mask < 16; mask <<= 1)
      bv = min(bv, __shfl_xor(bv, mask, 64));
    bv = __shfl(bv, 0, 64);
    cand[rsel] = bv & 8191;
    if (cv == bv) { cv = cv2; cv2 = 0x7FFFFFFF; }
  }
  const float4 xv = *(const float4*)(x + (size_t)row * DIM + lane * 4);
  float4 q0 = *(const float4*)(cb + (size_t)cand[0] * DIM + lane * 4);
  float4 q1 = *(const float4*)(cb + (size_t)cand[1] * DIM + lane * 4);
  float4 q2 = *(const float4*)(cb + (size_t)cand[2] * DIM + lane * 4);
  float4 q3 = *(const float4*)(cb + (size_t)cand[3] * DIM + lane * 4);
  float d0 = xv.x * q0.x + xv.y * q0.y + xv.z * q0.z + xv.w * q0.w;
  float d1 = xv.x * q1.x + xv.y * q1.y + xv.z * q1.z + xv.w * q1.w;
  float d2 = xv.x * q2.x + xv.y * q2.y + xv.z * q2.z + xv.w * q2.w;
  float d3 = xv.x * q3.x + xv.y * q3.y + xv.z * q3.z + xv.w * q3.w;
  float x2 = xv.x * xv.x + xv.y * xv.y + xv.z * xv.z + xv.w * xv.w;
#pragma unroll
  for (int mask = 1; mask < 64; mask <<= 1) {
    d0 += __shfl_xor(d0, mask, 64);
    d1 += __shfl_xor(d1, mask, 64);
    d2 += __shfl_xor(d2, mask, 64);
    d3 += __shfl_xor(d3, mask, 64);
    x2 += __shfl_xor(x2, mask, 64);
  }
  float e0 = fmaf(-2.0f, d0, c2g[cand[0]]);
  float e1 = fmaf(-2.0f, d1, c2g[cand[1]]);
  float e2 = fmaf(-2.0f, d2, c2g[cand[2]]);
  float e3 = fmaf(-2.0f, d3, c2g[cand[3]]);
  float best = e0; int bk = cand[0];
  if (e1 < best || (e1 == best && cand[1] < bk)) { best = e1; bk = cand[1]; }
  if (e2 < best || (e2 == best && cand[2] < bk)) { best = e2; bk = cand[2]; }
  if (e3 < best || (e3 == best && cand[3] < bk)) { best = e3; bk = cand[3]; }
  float4 q = (bk == cand[1]) ? q1 : (bk == cand[2]) ? q2 : (bk == cand[3]) ? q3 : q0;
  *(float4*)(out_q + (size_t)row * DIM + lane * 4) = q;
  if (lane == 0) {
    ind[row] = bk;
    out_ind[row] = (float)bk;
    atomicAdd(cnt + bk, 1);
    lsm[wid] = x2 + best;   // == ||q - x||^2 (exact identity)
  }
  __syncthreads();
  if (threadIdx.x == 0)
    loss_part[blockIdx.x] = lsm[0] + lsm[1] + lsm[2] + lsm[3];
}

// ---- scan: exclusive scan cnt -> offs/woffs; out_cs; reduce loss ----
__global__ __launch_bounds__(1024)
void vq_scan(const int* __restrict__ cnt, int* __restrict__ offs,
             int* __restrict__ woffs, float* __restrict__ out_cs,
             const float* __restrict__ loss_part, float* __restrict__ out_loss) {
  __shared__ int ssum[1024];
  __shared__ float sls[1024];
  int tid = threadIdx.x;
  int c[8], loc[8];
  int s = 0;
#pragma unroll
  for (int j = 0; j < 8; ++j) {
    c[j] = cnt[tid * 8 + j];
    loc[j] = s;
    s += c[j];
  }
  ssum[tid] = s;
  float ls = 0.0f;
#pragma unroll
  for (int j = 0; j < 8; ++j) ls += loss_part[tid * 8 + j];
  sls[tid] = ls;
  __syncthreads();
  for (int off = 1; off < 1024; off <<= 1) {
    int v = (tid >= off) ? ssum[tid - off] : 0;
    __syncthreads();
    ssum[tid] += v;
    __syncthreads();
  }
  int base = (tid > 0) ? ssum[tid - 1] : 0;
#pragma unroll
  for (int j = 0; j < 8; ++j) {
    int o = base + loc[j];
    offs[tid * 8 + j] = o;
    woffs[tid * 8 + j] = o;
    out_cs[tid * 8 + j] = (float)c[j];
  }
  for (int off = 512; off >= 1; off >>= 1) {
    if (tid < off) sls[tid] += sls[tid + off];
    __syncthreads();
  }
  if (tid == 0) *out_loss = sls[0] * (1.0f / 8388608.0f);
}

// ---- scatter: build rowlist grouped by code ----
__global__ __launch_bounds__(256)
void vq_scatter(const int* __restrict__ ind, int* __restrict__ woffs,
                int* __restrict__ rowlist) {
  int row = blockIdx.x * 256 + threadIdx.x;
  int k = ind[row];
  int pos = atomicAdd(woffs + k, 1);
  rowlist[pos] = row;
}

// ---- esum: ONE BLOCK (4 waves) PER CODE; unroll-4 ILP; LDS cross-wave ----
__global__ __launch_bounds__(256)
void vq_esum(const float* __restrict__ x, const int* __restrict__ offs,
             const int* __restrict__ cnt, const int* __restrict__ rowlist,
             float* __restrict__ out_es) {
  __shared__ float4 sred[3][64];
  int k = blockIdx.x;
  int wid = threadIdx.x >> 6, lane = threadIdx.x & 63;
  int start = offs[k], n = cnt[k];
  const int* rl = rowlist + start;
  int jb = (n * wid) >> 2, je = (n * (wid + 1)) >> 2;
  float4 acc = {0.f, 0.f, 0.f, 0.f};
  int j = jb;
  for (; j + 4 <= je; j += 4) {
    int r0 = rl[j], r1 = rl[j + 1], r2 = rl[j + 2], r3 = rl[j + 3];
    float4 v0 = *(const float4*)(x + (size_t)r0 * DIM + lane * 4);
    float4 v1 = *(const float4*)(x + (size_t)r1 * DIM + lane * 4);
    float4 v2 = *(const float4*)(x + (size_t)r2 * DIM + lane * 4);
    float4 v3 = *(const float4*)(x + (size_t)r3 * DIM + lane * 4);
    acc.x += v0.x + v1.x + v2.x + v3.x;
    acc.y += v0.y + v1.y + v2.y + v3.y;
    acc.z += v0.z + v1.z + v2.z + v3.z;
    acc.w += v0.w + v1.w + v2.w + v3.w;
  }
  for (; j < je; ++j) {
    int r = rl[j];
    float4 v = *(const float4*)(x + (size_t)r * DIM + lane * 4);
    acc.x += v.x; acc.y += v.y; acc.z += v.z; acc.w += v.w;
  }
  if (wid > 0) sred[wid - 1][lane] = acc;
  __syncthreads();
  if (wid == 0) {
    float4 a1 = sred[0][lane], a2 = sred[1][lane], a3 = sred[2][lane];
    acc.x += a1.x + a2.x + a3.x;
    acc.y += a1.y + a2.y + a3.y;
    acc.z += a1.z + a2.z + a3.z;
    acc.w += a1.w + a2.w + a3.w;
    *(float4*)(out_es + (size_t)k * DIM + lane * 4) = acc;
  }
}

extern "C" void kernel_launch(void* const* d_in, const int* in_sizes, int n_in,
                              void* d_out, int out_size, void* d_ws,
                              size_t ws_size, hipStream_t stream) {
  const float* x = (const float*)d_in[0];
  const float* cb = (const float*)d_in[1];
  float* out = (float*)d_out;
  float* out_q = out;
  float* out_ind = out + OUT_IND;
  float* out_loss = out + OUT_LOSS;
  float* out_cs = out + OUT_CS;
  float* out_es = out + OUT_ES;

  // Scratch-in-output (r16-23-proven layout):
  u8* Xi8 = (u8*)(out + XI8_OFF);
  u8* Ci8 = (u8*)(out + CI8_OFF);
  int2* partials = (int2*)(out + PART_OFF);

  // ws layout (448 KB; >= 2.21 MB proven available in round 1)
  char* w = (char*)d_ws;
  int* cnt = (int*)w;                              // 32 KB [zeroed in prep]
  int* offs = (int*)(w + (32 << 10));              // 32 KB
  int* woffs = (int*)(w + (64 << 10));             // 32 KB
  float* loss_part = (float*)(w + (96 << 10));     // 32 KB
  int* ind = (int*)(w + (128 << 10));              // 128 KB
  int* rowlist = (int*)(w + (256 << 10));          // 128 KB
  float* c2 = (float*)(w + (384 << 10));           // 32 KB
  int* c2i = (int*)(w + (416 << 10));              // 32 KB

  vq_prep<<<2560, 256, 0, stream>>>(x, cb, Xi8, Ci8, c2, c2i, cnt);
  vq_mfma<<<512, 256, 0, stream>>>(Xi8, Ci8, c2i, partials);
  vq_pick<<<BN_TOTAL / 4, 256, 0, stream>>>(x, cb, c2, partials, ind, out_ind,
                                            out_q, cnt, loss_part);
  vq_scan<<<1, 1024, 0, stream>>>(cnt, offs, woffs, out_cs, loss_part, out_loss);
  vq_scatter<<<BN_TOTAL / 256, 256, 0, stream>>>(ind, woffs, rowlist);
  vq_esum<<<KCODES, 256, 0, stream>>>(x, offs, cnt, rowlist, out_es);
}